// Round 10
// baseline (94300.519 us; speedup 1.0000x reference)
//
#include <hip/hip_runtime.h>

// ---------------------------------------------------------------------------
// fPEPS amplitude via boundary-MPS, chi=32. Metric ("left-Gram") formulation,
// f64 core with f32 bulk-tensor storage. Truncation = top eigvecs of M'^T G M'
// via in-LDS SHIFTED CholeskyQR subspace iteration (overflow-free, f64).
// Bottom & top chains fused per launch (blockIdx.z = sample*2+side).
// Lx=Ly=8, D=8, P=2, CHI=32.
//
// R1: cholqr solve -> in-LDS Rinv + staged GEMM. R2: workspace slim (single
// chunk). R4: 512-thread eig_sub, LDK=65, degree-2 schedule (->154.5k).
// R7: S2/S4 precomputed by batched k_mm; eig loop = 4x{Y=S4*Y; QR1} (->91k).
// R8: BARRIER DIET in eig path (~2500 -> ~1000 __syncthreads/launch):
//  - Jacobi 2 barriers/round; cholqr 64-row staging + zero-barrier
//    single-wave {shift,elim,normalize,Rinv}; smul/Ritz restaged.
// R9: identical resubmit (R8 bench infra-failed; measurement pending).
// ---------------------------------------------------------------------------

__host__ __device__ static inline int imin_(int a,int b){return a<b?a:b;}

static constexpr int SAMP_J = 991296;    // 7.93 MB/job
static constexpr int O_CUR = 0;
static constexpr int O_NEW = 65536;
static constexpr int O_TF  = 131072;
static constexpr int O_H2F = 393216;
static constexpr int O_MP  = 393216;
static constexpr int O_H   = 458752;     // H = G*M'; dead after k_mm_tn -> S2 temp
static constexpr int O_S   = 524288;
static constexpr int O_Y   = 589824;
static constexpr int O_Y2  = 606208;
static constexpr int O_C   = 622592;
static constexpr int O_V   = 630784;
static constexpr int O_GSB = 655360;
static constexpr int O_S4  = O_GSB + 266241;  // dead G^(6) slot

static const int goff[8] = {0,1,4097,69633,135169,200705,266241,331777};

#define LDK 65
// compiler memory fence: per-wave LDS is in-order on CDNA; this stops the
// compiler from reordering/caching LDS accesses across the point.
#define WMEMF() __asm__ volatile("" ::: "memory")

// ---------------------------------------------------------------------------
__global__ void k_init_row(double* ws, const float* peps, const int* x, int s0){
  int z=blockIdx.z, y=blockIdx.x;
  int side=z&1, samp=z>>1;
  int xi = side?7:0;
  double* base = ws + (size_t)z*SAMP_J;
  double* cur = base + O_CUR + y*8192;
  int spin = x[(s0+samp)*64 + xi*8 + y];
  const float* pb = peps + (size_t)xi*65536 + (size_t)y*8192 + spin;
  int rd=(y<7)?8:1, ld=(y>0)?8:1;
  int ntot = ld*rd*8;
  for(int e=threadIdx.x; e<ntot; e+=blockDim.x){
    int u=e&7; int r=(e>>3)%rd; int l=e/(8*rd);
    float v = side ? pb[u*128 + l*16 + r*2] : pb[u*1024 + l*16 + r*2];
    cur[e]=(double)v;
  }
  if(y==0 && threadIdx.x==0) base[O_GSB]=1.0;
}

// ---------------------------------------------------------------------------
__global__ __launch_bounds__(256)
void k_absorb(double* ws, const float* peps, const int* x, int s0,
              int xi_b, int xi_t, int y, int bl, int brdim){
  int z=blockIdx.z, yb=blockIdx.x;
  int side=z&1, samp=z>>1;
  int xi = side? xi_t : xi_b;
  int so = side? 128:1024, sc = side? 1024:128;
  double* base=ws+(size_t)z*SAMP_J;
  const double* B=base+O_CUR+y*8192;
  float* T=(float*)(base+O_TF);
  int spin=x[(s0+samp)*64+xi*8+y];
  const float* A=peps+(size_t)xi*65536+(size_t)y*8192+spin;
  int Lp=(y>0)?8:1, Rp=(y<7)?8:1;
  int rraw=brdim*Rp;
  __shared__ float As[4096];
  __shared__ double Bs[256];
  int nA=64*Lp*Rp;
  for(int e=threadIdx.x;e<nA;e+=256){
    int rp=e%Rp; int t=e/Rp; int lp=t%Lp; t/=Lp; int p=t&7; int u=t>>3;
    As[e]=A[u*so+p*sc+lp*16+rp*2];
  }
  for(int e=threadIdx.x;e<bl*8;e+=256)
    Bs[e]=B[((e>>3)*brdim+yb)*8+(e&7)];
  __syncthreads();
  int ntot=bl*Lp*Rp*8;
  for(int e=threadIdx.x;e<ntot;e+=256){
    int u=e&7; int t=e>>3; int rp=t%Rp; t/=Rp; int lp=t%Lp; int xx=t/Lp;
    double acc=0.0;
    #pragma unroll
    for(int p=0;p<8;p++) acc+=Bs[xx*8+p]*(double)As[((u*8+p)*Lp+lp)*Rp+rp];
    T[(size_t)((xx*Lp+lp)*rraw + yb*Rp+rp)*8 + u]=(float)acc;
  }
}

// ---------------------------------------------------------------------------
__global__ void k_mmGT(double* ws, int Aoff, int Boff, int Coff, int ni, int nk, int nj){
  double* base=ws+(size_t)blockIdx.z*SAMP_J;
  const double* A=base+Aoff;
  const float* B=(const float*)(base+Boff);
  float* C=(float*)(base+Coff);
  __shared__ double As[16][17]; __shared__ float Bs[16][17];
  int tx=threadIdx.x, ty=threadIdx.y;
  int i0=blockIdx.x*16, j0=blockIdx.y*16;
  double acc=0.0;
  for(int k0=0;k0<nk;k0+=16){
    As[ty][tx]=(i0+ty<ni && k0+tx<nk)? A[(size_t)(i0+ty)*nk + k0+tx] : 0.0;
    Bs[ty][tx]=(k0+ty<nk && j0+tx<nj)? B[(size_t)(k0+ty)*nj + j0+tx] : 0.f;
    __syncthreads();
    #pragma unroll
    for(int t=0;t<16;t++) acc+=As[ty][t]*(double)Bs[t][tx];
    __syncthreads();
  }
  if(i0+ty<ni && j0+tx<nj) C[(size_t)(i0+ty)*nj + j0+tx]=(float)acc;
}

__global__ void k_mm(double* ws, int Aoff, int Boff, int Coff, int ni, int nk, int nj){
  double* base=ws+(size_t)blockIdx.z*SAMP_J;
  const double* A=base+Aoff; const double* B=base+Boff; double* C=base+Coff;
  __shared__ double As[16][17], Bs[16][17];
  int tx=threadIdx.x, ty=threadIdx.y;
  int i0=blockIdx.x*16, j0=blockIdx.y*16;
  double acc=0.0;
  for(int k0=0;k0<nk;k0+=16){
    As[ty][tx]=(i0+ty<ni && k0+tx<nk)? A[(size_t)(i0+ty)*nk + k0+tx] : 0.0;
    Bs[ty][tx]=(k0+ty<nk && j0+tx<nj)? B[(size_t)(k0+ty)*nj + j0+tx] : 0.0;
    __syncthreads();
    #pragma unroll
    for(int t=0;t<16;t++) acc+=As[ty][t]*Bs[t][tx];
    __syncthreads();
  }
  if(i0+ty<ni && j0+tx<nj) C[(size_t)(i0+ty)*nj + j0+tx]=acc;
}
__global__ void k_mm_tn(double* ws, int Aoff, int Boff, int Coff, int ni, int nk, int nj){
  double* base=ws+(size_t)blockIdx.z*SAMP_J;
  const double* A=base+Aoff; const double* B=base+Boff; double* C=base+Coff;
  __shared__ double As[16][17], Bs[16][17];
  int tx=threadIdx.x, ty=threadIdx.y;
  int i0=blockIdx.x*16, j0=blockIdx.y*16;
  double acc=0.0;
  for(int k0=0;k0<nk;k0+=16){
    As[ty][tx]=(k0+ty<nk && i0+tx<ni)? A[(size_t)(k0+ty)*ni + i0+tx] : 0.0;
    Bs[ty][tx]=(k0+ty<nk && j0+tx<nj)? B[(size_t)(k0+ty)*nj + j0+tx] : 0.0;
    __syncthreads();
    #pragma unroll
    for(int t=0;t<16;t++) acc+=As[t][ty]*Bs[t][tx];
    __syncthreads();
  }
  if(i0+ty<ni && j0+tx<nj) C[(size_t)(i0+ty)*nj + j0+tx]=acc;
}

// ---------------------------------------------------------------------------
__global__ void k_gacc2(double* ws, int H2off, int Toff, int Goff, int ldim, int rdim){
  int bx=blockIdx.x, by=blockIdx.y;
  if(by<bx) return;
  double* base=ws+(size_t)blockIdx.z*SAMP_J;
  const float* H2=(const float*)(base+H2off);
  const float* T=(const float*)(base+Toff);
  double* G=base+Goff;
  __shared__ float As[16][17], Bs[16][17];
  int tx=threadIdx.x, ty=threadIdx.y;
  int r0=bx*16, r1=by*16;
  double acc=0.0;
  int ktot=ldim*8;
  for(int k0=0;k0<ktot;k0+=16){
    int kk=k0+ty; int l2=kk>>3; int u=kk&7;
    As[ty][tx]=(kk<ktot)? H2[((size_t)l2*rdim + r0+tx)*8 + u] : 0.f;
    Bs[ty][tx]=(kk<ktot)? T [((size_t)l2*rdim + r1+tx)*8 + u] : 0.f;
    __syncthreads();
    #pragma unroll
    for(int t=0;t<16;t++) acc+=(double)As[t][ty]*(double)Bs[t][tx];
    __syncthreads();
  }
  G[(size_t)(r0+ty)*rdim + r1+tx]=acc;
  if(by>bx) G[(size_t)(r1+tx)*rdim + r0+ty]=acc;
}

__global__ void k_gscale(double* ws, int Goff, int n){
  int tid=threadIdx.x;
  double* base=ws+(size_t)blockIdx.z*SAMP_J;
  double* G=base+Goff;
  __shared__ double red[256]; __shared__ double s_sc;
  double mx=0.0;
  for(int i=tid;i<n;i+=256) mx=fmax(mx,fabs(G[(size_t)i*n+i]));
  red[tid]=mx; __syncthreads();
  for(int w=128;w>0;w>>=1){ if(tid<w) red[tid]=fmax(red[tid],red[tid+w]); __syncthreads(); }
  if(tid==0) s_sc=(red[0]>0.0)?1.0/red[0]:1.0;
  __syncthreads();
  double sc=s_sc;
  for(int e=tid;e<n*n;e+=256) G[e]*=sc;
}

// ---------------------------------------------------------------------------
__global__ __launch_bounds__(256)
void k_mp(double* ws, int Toff, int Coff, int Moff, int rraw, int keep){
  int li=blockIdx.x, tid=threadIdx.x;
  double* base=ws+(size_t)blockIdx.z*SAMP_J;
  const float* T=(const float*)(base+Toff) + (size_t)li*rraw*8;
  const double* Cc=base+Coff;
  double* M=base+Moff+(size_t)li*keep*8;
  __shared__ float Ts[2048];
  for(int e=tid;e<rraw*8;e+=256) Ts[e]=T[e];
  __syncthreads();
  for(int e=tid;e<keep*8;e+=256){
    int u=e&7, k=e>>3;
    double acc=0.0;
    for(int r=0;r<rraw;r++) acc+=(double)Ts[r*8+u]*Cc[(size_t)r*keep+k];
    M[k*8+u]=acc;
  }
}

__global__ void k_t2mp(double* ws, int n){
  double* base=ws+(size_t)blockIdx.z*SAMP_J;
  const float* T=(const float*)(base+O_TF);
  for(int e=blockIdx.x*blockDim.x+threadIdx.x;e<n;e+=gridDim.x*blockDim.x)
    base[O_MP+e]=(double)T[e];
}

// ---------------------------------------------------------------------------
// Cyclic Jacobi, closed-form round-robin (circle method), stride LDK.
// 2 barriers/round: each lane of a pair-group redundantly computes (c,s)
// from its OWN rows (race-free), keeps them in registers for the col phase.
__device__ void dev_jacobi(double* K, float* W, int q, int tid, int sweeps){
  int NT=blockDim.x;
  int m=q-1, npairs=q>>1;
  int L=NT/npairs;
  int inv2=(m+1)>>1;
  int pr=tid/L, lane=tid%L;
  for(int sweep=0;sweep<sweeps;sweep++)
  for(int rnd=0;rnd<m;rnd++){
    int i0=(int)(((long long)rnd*(long long)inv2)%m);
    int p,qq;
    if(pr==0){ p=i0; qq=q-1; }
    else {
      p=i0+pr; if(p>=m) p-=m;
      qq=i0-pr; if(qq<0) qq+=m;
    }
    if(p>qq){int t=p;p=qq;qq=t;}
    // rotation from own rows (reads precede writes in lockstep program order)
    double c=1.0,s2=0.0;
    double apq=K[p*LDK+qq];
    double app=K[p*LDK+p], aqq=K[qq*LDK+qq];
    if(fabs(apq) > 1e-18*(fabs(app)+fabs(aqq))+1e-300){
      double tau=(aqq-app)/(2.0*apq);
      double t=(tau>=0.0?1.0:-1.0)/(fabs(tau)+sqrt(1.0+tau*tau));
      c=1.0/sqrt(1.0+t*t); s2=t*c;
    }
    // row update (rows p,qq owned by this group)
    for(int j=lane;j<q;j+=L){
      double kp=K[p*LDK+j], kq=K[qq*LDK+j];
      K[p*LDK+j]=c*kp-s2*kq; K[qq*LDK+j]=s2*kp+c*kq;
    }
    __syncthreads();
    // column update (cols p,qq owned by this group) + eigvec update
    {
      float cf=(float)c, sf=(float)s2;
      for(int j=lane;j<q;j+=L){
        double kp=K[j*LDK+p], kq=K[j*LDK+qq];
        K[j*LDK+p]=c*kp-s2*kq; K[j*LDK+qq]=s2*kp+c*kq;
        float wp=W[j*LDK+p], wq=W[j*LDK+qq];
        W[j*LDK+p]=cf*wp-sf*wq; W[j*LDK+qq]=sf*wp+cf*wq;
      }
    }
    __syncthreads();
  }
}

// parallel top-keep select: wave-0 argmax per pick
__device__ void dev_select(const double* K, int q, int keep, int tid,
                           double* evals, int* idxs){
  for(int a=tid;a<q;a+=blockDim.x) evals[a]=K[a*LDK+a];
  __syncthreads();
  if(tid<64){
    int a=tid;
    double v=(a<q)? evals[a] : -1.0e300;
    for(int j=0;j<keep;j++){
      double bv=v; int bi=a;
      for(int off=1;off<64;off<<=1){
        double ov=__shfl_xor(bv,off); int oi=__shfl_xor(bi,off);
        if(ov>bv || (ov==bv && oi<bi)){ bv=ov; bi=oi; }
      }
      if(a==bi) v=-1.0e300;
      if(tid==0) idxs[j]=bi;
    }
  }
  __syncthreads();
}

// f64 CGS2 of V columns (n rows, keep cols, row-major stride keep) [256 thr]
__device__ void dev_orthV(double* V, int n, int keep, double* red){
  int tid=threadIdx.x;
  for(int j=0;j<keep;j++){
    double vj=(tid<n)? V[(size_t)tid*keep+j] : 0.0;
    for(int pass=0;pass<2;pass++){
      for(int t=0;t<j;t++){
        double vt=(tid<n)? V[(size_t)tid*keep+t] : 0.0;
        double p=vj*vt;
        for(int off=1;off<64;off<<=1) p+=__shfl_xor(p,off);
        if((tid&63)==0) red[tid>>6]=p;
        __syncthreads();
        double d=red[0]+red[1]+red[2]+red[3];
        vj-=d*vt;
        __syncthreads();
      }
    }
    double p=vj*vj;
    for(int off=1;off<64;off<<=1) p+=__shfl_xor(p,off);
    if((tid&63)==0) red[tid>>6]=p;
    __syncthreads();
    double nrm=red[0]+red[1]+red[2]+red[3];
    vj=vj/sqrt(fmax(nrm,1e-300));
    if(tid<n) V[(size_t)tid*keep+j]=vj;
    __syncthreads();
  }
}

// ---------------------------------------------------------------------------
// direct path (ru<=64), 256 threads
__global__ __launch_bounds__(256)
void k_eig_direct(double* ws, int Soff, int MPoff, int l, int ru, int keep,
                  int newoff, int Coff){
  int tid=threadIdx.x;
  double* base=ws+(size_t)blockIdx.z*SAMP_J;
  const double* S=base+Soff;
  const double* MP=base+MPoff;
  double* C=base+Coff;
  double* NM=base+newoff;
  double* V=base+O_V;
  __shared__ double K[64*LDK];
  __shared__ float W[64*LDK];
  __shared__ double evals[64]; __shared__ int idxs[64];
  __shared__ double red[4];
  int q=ru;
  for(int e=tid;e<q*q;e+=256){
    int a=e/q,b=e%q;
    K[a*LDK+b]=0.5*(S[(size_t)a*q+b]+S[(size_t)b*q+a]);
    W[a*LDK+b]=(a==b)?1.f:0.f;
  }
  __syncthreads();
  dev_jacobi(K,W,q,tid,8);
  dev_select(K,q,keep,tid,evals,idxs);
  for(int e=tid;e<ru*keep;e+=256){
    int col=e/keep, j=e%keep;
    V[e]=(double)W[col*LDK+idxs[j]];
  }
  __syncthreads();
  dev_orthV(V,ru,keep,red);
  for(int e=tid;e<keep*ru;e+=256){
    int j=e/ru, col=e%ru;
    NM[e]=V[(size_t)col*keep+j];
  }
  for(int e=tid;e<l*keep;e+=256){
    int i=e/keep, j=e%keep;
    const double* Mi=MP+(size_t)i*ru;
    double acc=0.0;
    for(int c=0;c<ru;c++) acc+=Mi[c]*V[(size_t)c*keep+j];
    C[e]=acc;
  }
}

// ---------------------------------------------------------------------------
// Yout = A * Yin  (A 256x256 f64 global; Y 256x64 f64 global), 512 threads.
// 64-row Yt blocks: 9 barriers total.
__device__ void dev_smul(const double* A, const double* Yin, double* Yout,
                         double* Yt, int tid){
  double acc[32];
  int i=tid&255, j0=(tid>>8)*32;
  #pragma unroll
  for(int j=0;j<32;j++) acc[j]=0.0;
  for(int cb=0;cb<4;cb++){
    __syncthreads();
    for(int e=tid;e<4096;e+=512) Yt[e]=Yin[cb*4096+e];
    __syncthreads();
    const double* Arow=A+(size_t)i*256+cb*64;
    for(int c=0;c<64;c++){
      double sv=Arow[c];
      const double* Yr=Yt+c*64+j0;
      #pragma unroll
      for(int j=0;j<32;j++) acc[j]+=sv*Yr[j];
    }
  }
  #pragma unroll
  for(int j=0;j<32;j++) Yout[(size_t)i*64+j0+j]=acc[j];
  __syncthreads();
}

// ---------------------------------------------------------------------------
// SHIFTED CholeskyQR on Yg (256 x ncols, f64 global), 512 threads.
// Gram staged in 64/128-row Yt blocks; shift+elimination+normalize+Rinv run
// in a ZERO-barrier single-wave region (per-wave in-order LDS + fences);
// X = Y*Ri staged. ~19 barriers total (was ~134).
__device__ void dev_cholqr(double* Yg, int ncols, double* Kd, double* Yt,
                           double* Ri, int tid){
  int rowsb=4096/ncols; if(rowsb>256) rowsb=256;   // 64 (nc=64) | 128 (nc=32)
  int nblk=256/rowsb;                               // 4 | 2
  int n2=ncols*ncols;
  for(int e=tid;e<n2;e+=512) Kd[(e/ncols)*LDK+(e%ncols)]=0.0;
  for(int b=0;b<nblk;b++){
    __syncthreads();
    for(int e=tid;e<rowsb*ncols;e+=512) Yt[e]=Yg[(size_t)b*rowsb*ncols+e];
    __syncthreads();
    for(int e=tid;e<n2;e+=512){
      int a=e/ncols, cc=e%ncols;
      if(cc>=a){
        double acc=0.0;
        for(int r=0;r<rowsb;r++) acc+=Yt[r*ncols+a]*Yt[r*ncols+cc];
        Kd[a*LDK+cc]+=acc;
      }
    }
  }
  __syncthreads();
  // ---- single-wave region: lane k owns column k. No block barriers. ----
  if(tid<64){
    int k=tid;
    double dv=(k<ncols)? Kd[k*LDK+k] : 0.0;
    double tr=dv;
    for(int off=1;off<64;off<<=1) tr+=__shfl_xor(tr,off);
    double lam=(tr/ncols)*1e-14+1e-290;
    if(k<ncols){
      Kd[k*LDK+k]=dv+lam;
      WMEMF();
      // raw upper elimination; pivot clamp computed redundantly per lane
      for(int j=0;j<ncols;j++){
        double d=Kd[j*LDK+j];
        if(!(d>lam*0.25)) d=lam*0.25;
        if(k==j) Kd[j*LDK+j]=d;
        if(k>j){
          double invd=1.0/d;
          double kjk=Kd[j*LDK+k];
          for(int i=j+1;i<=k;i++)
            Kd[i*LDK+k]-=Kd[j*LDK+i]*kjk*invd;
        }
        WMEMF();
      }
      // normalize -> R (R_jj = sqrt(d_j)); inv-sqrt diag via Yt[0..ncols)
      double dk=Kd[k*LDK+k];
      Yt[k]=1.0/sqrt(dk);
      WMEMF();
      for(int i=0;i<k;i++) Kd[i*LDK+k]*=Yt[i];
      Kd[k*LDK+k]=dk*Yt[k];
      WMEMF();
      // Ri = R^{-1}, column k (reads finalized R rows; writes own column)
      Ri[k*66+k]=1.0/Kd[k*LDK+k];
      for(int i=k-1;i>=0;i--){
        double s=0.0;
        for(int kk=i+1;kk<=k;kk++) s+=Kd[i*LDK+kk]*Ri[kk*66+k];
        Ri[i*66+k]=-s/Kd[i*LDK+i];
      }
    }
  }
  __syncthreads();
  // ---- X = Y * Ri, staged ----
  {
    int j=tid%ncols, rg=tid/ncols;
    int rpt=(rowsb*ncols)/512;              // 8 for both ncols
    for(int b=0;b<nblk;b++){
      for(int e=tid;e<rowsb*ncols;e+=512) Yt[e]=Yg[(size_t)b*rowsb*ncols+e];
      __syncthreads();
      double xr[8];
      for(int r4=0;r4<rpt;r4++){
        int r=rg*rpt+r4;
        double acc=0.0;
        for(int kk=0;kk<=j;kk++) acc+=Yt[r*ncols+kk]*Ri[kk*66+j];
        xr[r4]=acc;
      }
      __syncthreads();
      for(int r4=0;r4<rpt;r4++){
        int r=rg*rpt+r4;
        Yg[(size_t)b*rowsb*ncols + r*ncols + j]=xr[r4];
      }
    }
  }
  __syncthreads();
}

// subspace path (ru==256): S4 precomputed by batched GEMM. Schedule:
// Ya=S4*Omega, QR2, 4x{Ya=S4*Ya; QR1}, QR, Ritz with S*Ya (S^20 filter).
__global__ __launch_bounds__(512,1)
void k_eig_sub(double* ws, int Soff, int S4off, int MPoff, int l, int keep,
               int newoff, int Coff){
  const int RU=256;
  int tid=threadIdx.x;
  double* base=ws+(size_t)blockIdx.z*SAMP_J;
  const double* S =base+Soff;
  const double* S4=base+S4off;
  const double* MP=base+MPoff;
  double* Ya=base+O_Y;
  double* Yb=base+O_Y2;
  double* V =base+O_V;
  double* C =base+Coff;
  double* NM=base+newoff;
  __shared__ double Kd[64*LDK];    // 33.3 KB
  __shared__ double Ri[64*66];     // 33.8 KB
  __shared__ float  Wf[64*LDK];    // 16.6 KB
  __shared__ double Yt[4096];      // 32 KB
  __shared__ unsigned long long om[256];
  __shared__ double evals[64]; __shared__ int idxs[64];

  // Omega sign table
  for(int c2=tid;c2<256;c2+=512){
    unsigned long long mask=0ull;
    for(int j=0;j<64;j++){
      unsigned h=(unsigned)(c2*1103515245u)^(unsigned)((j+1)*2654435761u);
      h^=h>>13; h*=0x9E3779B1u;
      mask |= ((unsigned long long)((h>>16)&1u))<<j;
    }
    om[c2]=mask;
  }
  __syncthreads();

  // Ya = S4 * Omega
  for(int e=tid;e<RU*64;e+=512){
    int i=e>>6, j=e&63;
    const double* Si=S4+(size_t)i*RU;
    double acc=0.0;
    for(int c2=0;c2<RU;c2++)
      acc += ((om[c2]>>j)&1ull)? Si[c2] : -Si[c2];
    Ya[e]=acc;
  }
  __syncthreads();
  dev_cholqr(Ya,64,Kd,Yt,Ri,tid);
  dev_cholqr(Ya,64,Kd,Yt,Ri,tid);
  for(int it=0;it<4;it++){
    dev_smul(S4,Ya,Yb,Yt,tid);
    double* t=Ya; Ya=Yb; Yb=t;
    dev_cholqr(Ya,64,Kd,Yt,Ri,tid);
  }
  dev_cholqr(Ya,64,Kd,Yt,Ri,tid);   // tighten pre-Ritz
  dev_smul(S,Ya,Yb,Yt,tid);         // Yb = S*Ya (unorthogonalized)

  // Ritz: K = Ya^T Yb, staged 32 rows of each per block
  for(int e=tid;e<4096;e+=512){ int a=e>>6,c=e&63; Kd[a*LDK+c]=0.0; }
  for(int b=0;b<8;b++){
    __syncthreads();
    for(int e=tid;e<2048;e+=512){ Yt[e]=Ya[b*2048+e]; Yt[2048+e]=Yb[b*2048+e]; }
    __syncthreads();
    for(int e=tid;e<4096;e+=512){
      int a=e>>6, c=e&63;
      double acc=Kd[a*LDK+c];
      for(int r=0;r<32;r++) acc+=Yt[r*64+a]*Yt[2048+r*64+c];
      Kd[a*LDK+c]=acc;
    }
  }
  __syncthreads();
  for(int e=tid;e<4096;e+=512){
    int a=e>>6,c=e&63;
    if(a<c){ double m=0.5*(Kd[a*LDK+c]+Kd[c*LDK+a]); Kd[a*LDK+c]=m; Kd[c*LDK+a]=m; }
  }
  __syncthreads();
  for(int e=tid;e<4096;e+=512){ int a=e>>6,c=e&63; Wf[a*LDK+c]=(a==c)?1.f:0.f; }
  __syncthreads();
  dev_jacobi(Kd,Wf,64,tid,6);
  dev_select(Kd,64,keep,tid,evals,idxs);
  // V = Ya * W[:,sel]
  for(int e=tid;e<RU*keep;e+=512){
    int i=e/keep, j=e%keep; int vj=idxs[j];
    const double* Yr=Ya+(size_t)i*64;
    double acc=0.0;
    for(int t=0;t<64;t++) acc+=Yr[t]*(double)Wf[t*LDK+vj];
    V[e]=acc;
  }
  __syncthreads();
  dev_cholqr(V,keep,Kd,Yt,Ri,tid);   // f64 exact-projector fix
  for(int e=tid;e<keep*RU;e+=512){
    int j=e/RU, col=e%RU;
    NM[e]=V[(size_t)col*keep+j];
  }
  for(int e=tid;e<l*keep;e+=512){
    int i=e/keep, j=e%keep;
    const double* Mi=MP+(size_t)i*RU;
    double acc=0.0;
    for(int col=0;col<RU;col++) acc+=Mi[col]*V[(size_t)col*keep+j];
    C[e]=acc;
  }
}

// ---------------------------------------------------------------------------
__global__ void k_copy(double* ws){
  double* base=ws+(size_t)blockIdx.z*SAMP_J;
  for(int e=blockIdx.x*blockDim.x+threadIdx.x;e<65536;e+=gridDim.x*blockDim.x)
    base[O_CUR+e]=base[O_NEW+e];
}

__global__ __launch_bounds__(256)
void k_final(double* ws, float* out, int s0){
  int z=blockIdx.z, tid=threadIdx.x;
  const double* bot=ws+(size_t)(2*z)*SAMP_J+O_CUR;
  const double* top=ws+(size_t)(2*z+1)*SAMP_J+O_CUR;
  __shared__ double v[1024], v2[1024];
  __shared__ float w[8192];
  const int Bf[9]={1,8,32,32,32,32,32,8,1};
  if(tid==0) v[0]=1.0;
  __syncthreads();
  for(int y=0;y<8;y++){
    int a=Bf[y], b=Bf[y+1];
    const double* By=bot+y*8192;
    const double* Ty=top+y*8192;
    for(int e=tid;e<a*b*8;e+=256){
      int k2=e&7; int bb=(e>>3)%b; int cc=e/(8*b);
      double acc=0.0;
      for(int aa=0;aa<a;aa++) acc+=v[aa*a+cc]*By[(aa*b+bb)*8+k2];
      w[(cc*b+bb)*8+k2]=(float)acc;
    }
    __syncthreads();
    for(int e=tid;e<b*b;e+=256){
      int dd=e%b; int bb=e/b;
      double acc=0.0;
      for(int cc=0;cc<a;cc++)
        for(int k2=0;k2<8;k2++)
          acc+=(double)w[(cc*b+bb)*8+k2]*Ty[(cc*b+dd)*8+k2];
      v2[bb*b+dd]=acc;
    }
    __syncthreads();
    for(int e=tid;e<b*b;e+=256) v[e]=v2[e];
    __syncthreads();
  }
  if(tid==0) out[s0+z]=(float)v[0];
}

// ---------------------------------------------------------------------------
static void run_compress_dual(double* ws, const float* peps, const int* x,
                              int s0, int ns, int xib, int xit, bool first,
                              hipStream_t stream){
  int njobs=2*ns;
  int Bin[9]; Bin[0]=1; Bin[8]=1;
  for(int i=1;i<8;i++) Bin[i]= first?8:((i==1||i==7)?8:32);
  int lraw[8], rraw[8];
  for(int y=0;y<8;y++){ lraw[y]=Bin[y]*((y>0)?8:1); rraw[y]=Bin[y+1]*((y<7)?8:1); }
  int kch[8];
  { int kp=1;
    for(int y=0;y<8;y++){ int n=(y<7)?Bin[y+1]*8:1; kch[y]=imin_(kp*8,n); kp=kch[y]; } }
  int keep[8];
  keep[7]=imin_(32, imin_(kch[6], 8));
  for(int y=6;y>=1;y--) keep[y]=imin_(32, imin_(kch[y-1], keep[y+1]*8));

  // forward: G^(1..7)
  for(int y=0;y<7;y++){
    k_absorb<<<dim3(Bin[y+1],1,njobs),256,0,stream>>>(ws,peps,x,s0,xib,xit,y,Bin[y],Bin[y+1]);
    int l=lraw[y], r8=rraw[y]*8;
    k_mmGT<<<dim3((l+15)/16,(r8+15)/16,njobs),dim3(16,16),0,stream>>>(
        ws,O_GSB+goff[y],O_TF,O_H2F,l,l,r8);
    k_gacc2<<<dim3(rraw[y]/16,rraw[y]/16,njobs),dim3(16,16),0,stream>>>(
        ws,O_H2F,O_TF,O_GSB+goff[y+1],l,rraw[y]);
    k_gscale<<<dim3(1,1,njobs),256,0,stream>>>(ws,O_GSB+goff[y+1],rraw[y]);
  }
  // backward
  for(int y=7;y>=1;y--){
    k_absorb<<<dim3(Bin[y+1],1,njobs),256,0,stream>>>(ws,peps,x,s0,xib,xit,y,Bin[y],Bin[y+1]);
    int ru=(y==7)?8:keep[y+1]*8;
    if(y==7) k_t2mp<<<dim3(2,1,njobs),256,0,stream>>>(ws,lraw[7]*8);
    else     k_mp<<<dim3(lraw[y],1,njobs),256,0,stream>>>(ws,O_TF,O_C,O_MP,rraw[y],keep[y+1]);
    int l=lraw[y];
    k_mm<<<dim3((l+15)/16,(ru+15)/16,njobs),dim3(16,16),0,stream>>>(
        ws,O_GSB+goff[y],O_MP,O_H,l,l,ru);
    k_mm_tn<<<dim3((ru+15)/16,(ru+15)/16,njobs),dim3(16,16),0,stream>>>(
        ws,O_MP,O_H,O_S,ru,l,ru);
    if(ru<=64){
      k_eig_direct<<<dim3(1,1,njobs),256,0,stream>>>(ws,O_S,O_MP,l,ru,keep[y],
                    O_NEW+y*8192,O_C);
    } else {
      // S2 = S*S into O_H (dead), S4 = S2*S2 into O_S4 (dead G^(6) slot)
      k_mm<<<dim3(16,16,njobs),dim3(16,16),0,stream>>>(ws,O_S,O_S,O_H,256,256,256);
      k_mm<<<dim3(16,16,njobs),dim3(16,16),0,stream>>>(ws,O_H,O_H,O_S4,256,256,256);
      k_eig_sub<<<dim3(1,1,njobs),512,0,stream>>>(ws,O_S,O_S4,O_MP,l,keep[y],
                    O_NEW+y*8192,O_C);
    }
  }
  // site 0
  k_absorb<<<dim3(Bin[1],1,njobs),256,0,stream>>>(ws,peps,x,s0,xib,xit,0,1,Bin[1]);
  k_mp<<<dim3(1,1,njobs),256,0,stream>>>(ws,O_TF,O_C,O_NEW+0,rraw[0],keep[1]);
  k_copy<<<dim3(32,1,njobs),256,0,stream>>>(ws);
}

extern "C" void kernel_launch(void* const* d_in, const int* in_sizes, int n_in,
                              void* d_out, int out_size, void* d_ws, size_t ws_size,
                              hipStream_t stream){
  const int*   x    = (const int*)d_in[0];     // (16,64) int32
  const float* peps = (const float*)d_in[1];   // (8,8,8,8,8,8,2) f32
  float* out = (float*)d_out;                  // 16 f32
  double* ws = (double*)d_ws;
  size_t samp_bytes = (size_t)2*SAMP_J*sizeof(double);
  int max_chunk=(int)(ws_size/samp_bytes);
  if(max_chunk<1) max_chunk=1;
  if(max_chunk>16) max_chunk=16;
  for(int s0=0;s0<16;s0+=max_chunk){
    int ns=imin_(max_chunk,16-s0);
    int njobs=2*ns;
    k_init_row<<<dim3(8,1,njobs),64,0,stream>>>(ws,peps,x,s0);
    run_compress_dual(ws,peps,x,s0,ns,1,6,true ,stream);
    run_compress_dual(ws,peps,x,s0,ns,2,5,false,stream);
    run_compress_dual(ws,peps,x,s0,ns,3,4,false,stream);
    k_final<<<dim3(1,1,ns),256,0,stream>>>(ws,out,s0);
  }
}

// Round 15
// 86070.850 us; speedup vs baseline: 1.0956x; 1.0956x over previous
//
#include <hip/hip_runtime.h>

// ---------------------------------------------------------------------------
// fPEPS amplitude via boundary-MPS, chi=32. Metric ("left-Gram") formulation,
// f64 core with f32 bulk-tensor storage. Truncation = top eigvecs of M'^T G M'
// via in-LDS SHIFTED CholeskyQR subspace iteration (overflow-free, f64).
// Bottom & top chains fused per launch (blockIdx.z = sample*2+side).
// Lx=Ly=8, D=8, P=2, CHI=32.
//
// R1: cholqr solve -> in-LDS Rinv + staged GEMM. R2: workspace slim (single
// chunk). R4: 512-thread eig_sub, LDK=65, degree-2 schedule (->154.5k).
// R7: S2/S4 precomputed by batched k_mm (->91k). R8: barrier diet in eig
// path (measured R10: 94.3k — NULL vs R7; eig_sub latency/issue-bound).
// R10: REGISTER-TILED batch GEMMs — k_gacc2/k_mmGT/k_mm/k_mm_tn get
// 32x32 tiles, 2x2 micro per thread (ILP 4), k-tile 32 (k_gacc2 was
// 0.3 TF/s). Math order unchanged. Eig path byte-identical to R8.
// R11-R14: identical resubmits (bench infra-failed; measurement pending).
// ---------------------------------------------------------------------------

__host__ __device__ static inline int imin_(int a,int b){return a<b?a:b;}

static constexpr int SAMP_J = 991296;    // 7.93 MB/job
static constexpr int O_CUR = 0;
static constexpr int O_NEW = 65536;
static constexpr int O_TF  = 131072;
static constexpr int O_H2F = 393216;
static constexpr int O_MP  = 393216;
static constexpr int O_H   = 458752;     // H = G*M'; dead after k_mm_tn -> S2 temp
static constexpr int O_S   = 524288;
static constexpr int O_Y   = 589824;
static constexpr int O_Y2  = 606208;
static constexpr int O_C   = 622592;
static constexpr int O_V   = 630784;
static constexpr int O_GSB = 655360;
static constexpr int O_S4  = O_GSB + 266241;  // dead G^(6) slot

static const int goff[8] = {0,1,4097,69633,135169,200705,266241,331777};

#define LDK 65
#define WMEMF() __asm__ volatile("" ::: "memory")

// ---------------------------------------------------------------------------
__global__ void k_init_row(double* ws, const float* peps, const int* x, int s0){
  int z=blockIdx.z, y=blockIdx.x;
  int side=z&1, samp=z>>1;
  int xi = side?7:0;
  double* base = ws + (size_t)z*SAMP_J;
  double* cur = base + O_CUR + y*8192;
  int spin = x[(s0+samp)*64 + xi*8 + y];
  const float* pb = peps + (size_t)xi*65536 + (size_t)y*8192 + spin;
  int rd=(y<7)?8:1, ld=(y>0)?8:1;
  int ntot = ld*rd*8;
  for(int e=threadIdx.x; e<ntot; e+=blockDim.x){
    int u=e&7; int r=(e>>3)%rd; int l=e/(8*rd);
    float v = side ? pb[u*128 + l*16 + r*2] : pb[u*1024 + l*16 + r*2];
    cur[e]=(double)v;
  }
  if(y==0 && threadIdx.x==0) base[O_GSB]=1.0;
}

// ---------------------------------------------------------------------------
__global__ __launch_bounds__(256)
void k_absorb(double* ws, const float* peps, const int* x, int s0,
              int xi_b, int xi_t, int y, int bl, int brdim){
  int z=blockIdx.z, yb=blockIdx.x;
  int side=z&1, samp=z>>1;
  int xi = side? xi_t : xi_b;
  int so = side? 128:1024, sc = side? 1024:128;
  double* base=ws+(size_t)z*SAMP_J;
  const double* B=base+O_CUR+y*8192;
  float* T=(float*)(base+O_TF);
  int spin=x[(s0+samp)*64+xi*8+y];
  const float* A=peps+(size_t)xi*65536+(size_t)y*8192+spin;
  int Lp=(y>0)?8:1, Rp=(y<7)?8:1;
  int rraw=brdim*Rp;
  __shared__ float As[4096];
  __shared__ double Bs[256];
  int nA=64*Lp*Rp;
  for(int e=threadIdx.x;e<nA;e+=256){
    int rp=e%Rp; int t=e/Rp; int lp=t%Lp; t/=Lp; int p=t&7; int u=t>>3;
    As[e]=A[u*so+p*sc+lp*16+rp*2];
  }
  for(int e=threadIdx.x;e<bl*8;e+=256)
    Bs[e]=B[((e>>3)*brdim+yb)*8+(e&7)];
  __syncthreads();
  int ntot=bl*Lp*Rp*8;
  for(int e=threadIdx.x;e<ntot;e+=256){
    int u=e&7; int t=e>>3; int rp=t%Rp; t/=Rp; int lp=t%Lp; int xx=t/Lp;
    double acc=0.0;
    #pragma unroll
    for(int p=0;p<8;p++) acc+=Bs[xx*8+p]*(double)As[((u*8+p)*Lp+lp)*Rp+rp];
    T[(size_t)((xx*Lp+lp)*rraw + yb*Rp+rp)*8 + u]=(float)acc;
  }
}

// ---------------------------------------------------------------------------
// H2(f32) = G(f64) * T(f32): (ni x nk)(nk x nj). 32x32 tile, 2x2 micro.
__global__ __launch_bounds__(256)
void k_mmGT(double* ws, int Aoff, int Boff, int Coff, int ni, int nk, int nj){
  double* base=ws+(size_t)blockIdx.z*SAMP_J;
  const double* A=base+Aoff;
  const float* B=(const float*)(base+Boff);
  float* C=(float*)(base+Coff);
  __shared__ double As[32][34];   // [k][i]
  __shared__ float  Bs[32][34];   // [k][j]
  int tx=threadIdx.x, ty=threadIdx.y;
  int i0=blockIdx.x*32, j0=blockIdx.y*32;
  double a00=0,a01=0,a10=0,a11=0;
  for(int k0=0;k0<nk;k0+=32){
    #pragma unroll
    for(int q=0;q<2;q++){
      int ii=ty+q*16;
      #pragma unroll
      for(int p=0;p<2;p++){
        int t=tx+p*16; int kk=k0+t;
        As[t][ii]=(i0+ii<ni && kk<nk)? A[(size_t)(i0+ii)*nk + kk] : 0.0;
      }
    }
    #pragma unroll
    for(int q=0;q<2;q++){
      int t=ty+q*16; int kk=k0+t;
      #pragma unroll
      for(int p=0;p<2;p++){
        int jj=tx+p*16;
        Bs[t][jj]=(kk<nk && j0+jj<nj)? B[(size_t)kk*nj + j0+jj] : 0.f;
      }
    }
    __syncthreads();
    #pragma unroll
    for(int t=0;t<32;t++){
      double av0=As[t][ty], av1=As[t][ty+16];
      double bv0=(double)Bs[t][tx], bv1=(double)Bs[t][tx+16];
      a00+=av0*bv0; a01+=av0*bv1; a10+=av1*bv0; a11+=av1*bv1;
    }
    __syncthreads();
  }
  if(i0+ty<ni    && j0+tx<nj)    C[(size_t)(i0+ty)*nj + j0+tx]=(float)a00;
  if(i0+ty<ni    && j0+tx+16<nj) C[(size_t)(i0+ty)*nj + j0+tx+16]=(float)a01;
  if(i0+ty+16<ni && j0+tx<nj)    C[(size_t)(i0+ty+16)*nj + j0+tx]=(float)a10;
  if(i0+ty+16<ni && j0+tx+16<nj) C[(size_t)(i0+ty+16)*nj + j0+tx+16]=(float)a11;
}

// f64 C = A*B. 32x32 tile, 2x2 micro.
__global__ __launch_bounds__(256)
void k_mm(double* ws, int Aoff, int Boff, int Coff, int ni, int nk, int nj){
  double* base=ws+(size_t)blockIdx.z*SAMP_J;
  const double* A=base+Aoff; const double* B=base+Boff; double* C=base+Coff;
  __shared__ double As[32][34];   // [k][i]
  __shared__ double Bs[32][34];   // [k][j]
  int tx=threadIdx.x, ty=threadIdx.y;
  int i0=blockIdx.x*32, j0=blockIdx.y*32;
  double a00=0,a01=0,a10=0,a11=0;
  for(int k0=0;k0<nk;k0+=32){
    #pragma unroll
    for(int q=0;q<2;q++){
      int ii=ty+q*16;
      #pragma unroll
      for(int p=0;p<2;p++){
        int t=tx+p*16; int kk=k0+t;
        As[t][ii]=(i0+ii<ni && kk<nk)? A[(size_t)(i0+ii)*nk + kk] : 0.0;
      }
    }
    #pragma unroll
    for(int q=0;q<2;q++){
      int t=ty+q*16; int kk=k0+t;
      #pragma unroll
      for(int p=0;p<2;p++){
        int jj=tx+p*16;
        Bs[t][jj]=(kk<nk && j0+jj<nj)? B[(size_t)kk*nj + j0+jj] : 0.0;
      }
    }
    __syncthreads();
    #pragma unroll
    for(int t=0;t<32;t++){
      double av0=As[t][ty], av1=As[t][ty+16];
      double bv0=Bs[t][tx], bv1=Bs[t][tx+16];
      a00+=av0*bv0; a01+=av0*bv1; a10+=av1*bv0; a11+=av1*bv1;
    }
    __syncthreads();
  }
  if(i0+ty<ni    && j0+tx<nj)    C[(size_t)(i0+ty)*nj + j0+tx]=a00;
  if(i0+ty<ni    && j0+tx+16<nj) C[(size_t)(i0+ty)*nj + j0+tx+16]=a01;
  if(i0+ty+16<ni && j0+tx<nj)    C[(size_t)(i0+ty+16)*nj + j0+tx]=a10;
  if(i0+ty+16<ni && j0+tx+16<nj) C[(size_t)(i0+ty+16)*nj + j0+tx+16]=a11;
}

// f64 C = A^T*B (A is nk x ni). 32x32 tile, 2x2 micro.
__global__ __launch_bounds__(256)
void k_mm_tn(double* ws, int Aoff, int Boff, int Coff, int ni, int nk, int nj){
  double* base=ws+(size_t)blockIdx.z*SAMP_J;
  const double* A=base+Aoff; const double* B=base+Boff; double* C=base+Coff;
  __shared__ double As[32][34];   // [k][i]
  __shared__ double Bs[32][34];   // [k][j]
  int tx=threadIdx.x, ty=threadIdx.y;
  int i0=blockIdx.x*32, j0=blockIdx.y*32;
  double a00=0,a01=0,a10=0,a11=0;
  for(int k0=0;k0<nk;k0+=32){
    #pragma unroll
    for(int q=0;q<2;q++){
      int t=ty+q*16; int kk=k0+t;
      #pragma unroll
      for(int p=0;p<2;p++){
        int ii=tx+p*16;
        As[t][ii]=(kk<nk && i0+ii<ni)? A[(size_t)kk*ni + i0+ii] : 0.0;
        Bs[t][ii]=(kk<nk && j0+ii<nj)? B[(size_t)kk*nj + j0+ii] : 0.0;
      }
    }
    __syncthreads();
    #pragma unroll
    for(int t=0;t<32;t++){
      double av0=As[t][ty], av1=As[t][ty+16];
      double bv0=Bs[t][tx], bv1=Bs[t][tx+16];
      a00+=av0*bv0; a01+=av0*bv1; a10+=av1*bv0; a11+=av1*bv1;
    }
    __syncthreads();
  }
  if(i0+ty<ni    && j0+tx<nj)    C[(size_t)(i0+ty)*nj + j0+tx]=a00;
  if(i0+ty<ni    && j0+tx+16<nj) C[(size_t)(i0+ty)*nj + j0+tx+16]=a01;
  if(i0+ty+16<ni && j0+tx<nj)    C[(size_t)(i0+ty+16)*nj + j0+tx]=a10;
  if(i0+ty+16<ni && j0+tx+16<nj) C[(size_t)(i0+ty+16)*nj + j0+tx+16]=a11;
}

// ---------------------------------------------------------------------------
// G'(f64)[r][r'] = sum_{l,u} H2f[(l r u)] * Tf[(l r' u)]; 32x32 tile, 2x2
// micro; upper blocks + mirror. rdim always multiple of 32 here.
__global__ __launch_bounds__(256)
void k_gacc2(double* ws, int H2off, int Toff, int Goff, int ldim, int rdim){
  int bx=blockIdx.x, by=blockIdx.y;
  if(by<bx) return;
  double* base=ws+(size_t)blockIdx.z*SAMP_J;
  const float* H2=(const float*)(base+H2off);
  const float* T=(const float*)(base+Toff);
  double* G=base+Goff;
  __shared__ float As[32][34], Bs[32][34];   // [k][r]
  int tx=threadIdx.x, ty=threadIdx.y;
  int r0=bx*32, r1=by*32;
  double a00=0,a01=0,a10=0,a11=0;
  int ktot=ldim*8;
  for(int k0=0;k0<ktot;k0+=32){
    #pragma unroll
    for(int q=0;q<2;q++){
      int t=ty+q*16; int kk=k0+t;
      int l2=kk>>3, u=kk&7;
      bool ok=kk<ktot;
      #pragma unroll
      for(int p=0;p<2;p++){
        int rr=tx+p*16;
        As[t][rr]= ok? H2[((size_t)l2*rdim + r0+rr)*8 + u] : 0.f;
        Bs[t][rr]= ok? T [((size_t)l2*rdim + r1+rr)*8 + u] : 0.f;
      }
    }
    __syncthreads();
    #pragma unroll
    for(int t=0;t<32;t++){
      double av0=(double)As[t][ty], av1=(double)As[t][ty+16];
      double bv0=(double)Bs[t][tx], bv1=(double)Bs[t][tx+16];
      a00+=av0*bv0; a01+=av0*bv1; a10+=av1*bv0; a11+=av1*bv1;
    }
    __syncthreads();
  }
  G[(size_t)(r0+ty)*rdim + r1+tx]=a00;
  G[(size_t)(r0+ty)*rdim + r1+tx+16]=a01;
  G[(size_t)(r0+ty+16)*rdim + r1+tx]=a10;
  G[(size_t)(r0+ty+16)*rdim + r1+tx+16]=a11;
  if(by>bx){
    G[(size_t)(r1+tx)*rdim + r0+ty]=a00;
    G[(size_t)(r1+tx+16)*rdim + r0+ty]=a01;
    G[(size_t)(r1+tx)*rdim + r0+ty+16]=a10;
    G[(size_t)(r1+tx+16)*rdim + r0+ty+16]=a11;
  }
}

__global__ void k_gscale(double* ws, int Goff, int n){
  int tid=threadIdx.x;
  double* base=ws+(size_t)blockIdx.z*SAMP_J;
  double* G=base+Goff;
  __shared__ double red[256]; __shared__ double s_sc;
  double mx=0.0;
  for(int i=tid;i<n;i+=256) mx=fmax(mx,fabs(G[(size_t)i*n+i]));
  red[tid]=mx; __syncthreads();
  for(int w=128;w>0;w>>=1){ if(tid<w) red[tid]=fmax(red[tid],red[tid+w]); __syncthreads(); }
  if(tid==0) s_sc=(red[0]>0.0)?1.0/red[0]:1.0;
  __syncthreads();
  double sc=s_sc;
  for(int e=tid;e<n*n;e+=256) G[e]*=sc;
}

// ---------------------------------------------------------------------------
__global__ __launch_bounds__(256)
void k_mp(double* ws, int Toff, int Coff, int Moff, int rraw, int keep){
  int li=blockIdx.x, tid=threadIdx.x;
  double* base=ws+(size_t)blockIdx.z*SAMP_J;
  const float* T=(const float*)(base+Toff) + (size_t)li*rraw*8;
  const double* Cc=base+Coff;
  double* M=base+Moff+(size_t)li*keep*8;
  __shared__ float Ts[2048];
  for(int e=tid;e<rraw*8;e+=256) Ts[e]=T[e];
  __syncthreads();
  for(int e=tid;e<keep*8;e+=256){
    int u=e&7, k=e>>3;
    double acc=0.0;
    for(int r=0;r<rraw;r++) acc+=(double)Ts[r*8+u]*Cc[(size_t)r*keep+k];
    M[k*8+u]=acc;
  }
}

__global__ void k_t2mp(double* ws, int n){
  double* base=ws+(size_t)blockIdx.z*SAMP_J;
  const float* T=(const float*)(base+O_TF);
  for(int e=blockIdx.x*blockDim.x+threadIdx.x;e<n;e+=gridDim.x*blockDim.x)
    base[O_MP+e]=(double)T[e];
}

// ---------------------------------------------------------------------------
// Cyclic Jacobi, closed-form round-robin (circle method), stride LDK.
// 2 barriers/round.
__device__ void dev_jacobi(double* K, float* W, int q, int tid, int sweeps){
  int NT=blockDim.x;
  int m=q-1, npairs=q>>1;
  int L=NT/npairs;
  int inv2=(m+1)>>1;
  int pr=tid/L, lane=tid%L;
  for(int sweep=0;sweep<sweeps;sweep++)
  for(int rnd=0;rnd<m;rnd++){
    int i0=(int)(((long long)rnd*(long long)inv2)%m);
    int p,qq;
    if(pr==0){ p=i0; qq=q-1; }
    else {
      p=i0+pr; if(p>=m) p-=m;
      qq=i0-pr; if(qq<0) qq+=m;
    }
    if(p>qq){int t=p;p=qq;qq=t;}
    double c=1.0,s2=0.0;
    double apq=K[p*LDK+qq];
    double app=K[p*LDK+p], aqq=K[qq*LDK+qq];
    if(fabs(apq) > 1e-18*(fabs(app)+fabs(aqq))+1e-300){
      double tau=(aqq-app)/(2.0*apq);
      double t=(tau>=0.0?1.0:-1.0)/(fabs(tau)+sqrt(1.0+tau*tau));
      c=1.0/sqrt(1.0+t*t); s2=t*c;
    }
    for(int j=lane;j<q;j+=L){
      double kp=K[p*LDK+j], kq=K[qq*LDK+j];
      K[p*LDK+j]=c*kp-s2*kq; K[qq*LDK+j]=s2*kp+c*kq;
    }
    __syncthreads();
    {
      float cf=(float)c, sf=(float)s2;
      for(int j=lane;j<q;j+=L){
        double kp=K[j*LDK+p], kq=K[j*LDK+qq];
        K[j*LDK+p]=c*kp-s2*kq; K[j*LDK+qq]=s2*kp+c*kq;
        float wp=W[j*LDK+p], wq=W[j*LDK+qq];
        W[j*LDK+p]=cf*wp-sf*wq; W[j*LDK+qq]=sf*wp+cf*wq;
      }
    }
    __syncthreads();
  }
}

// parallel top-keep select: wave-0 argmax per pick
__device__ void dev_select(const double* K, int q, int keep, int tid,
                           double* evals, int* idxs){
  for(int a=tid;a<q;a+=blockDim.x) evals[a]=K[a*LDK+a];
  __syncthreads();
  if(tid<64){
    int a=tid;
    double v=(a<q)? evals[a] : -1.0e300;
    for(int j=0;j<keep;j++){
      double bv=v; int bi=a;
      for(int off=1;off<64;off<<=1){
        double ov=__shfl_xor(bv,off); int oi=__shfl_xor(bi,off);
        if(ov>bv || (ov==bv && oi<bi)){ bv=ov; bi=oi; }
      }
      if(a==bi) v=-1.0e300;
      if(tid==0) idxs[j]=bi;
    }
  }
  __syncthreads();
}

// f64 CGS2 of V columns (n rows, keep cols, row-major stride keep) [256 thr]
__device__ void dev_orthV(double* V, int n, int keep, double* red){
  int tid=threadIdx.x;
  for(int j=0;j<keep;j++){
    double vj=(tid<n)? V[(size_t)tid*keep+j] : 0.0;
    for(int pass=0;pass<2;pass++){
      for(int t=0;t<j;t++){
        double vt=(tid<n)? V[(size_t)tid*keep+t] : 0.0;
        double p=vj*vt;
        for(int off=1;off<64;off<<=1) p+=__shfl_xor(p,off);
        if((tid&63)==0) red[tid>>6]=p;
        __syncthreads();
        double d=red[0]+red[1]+red[2]+red[3];
        vj-=d*vt;
        __syncthreads();
      }
    }
    double p=vj*vj;
    for(int off=1;off<64;off<<=1) p+=__shfl_xor(p,off);
    if((tid&63)==0) red[tid>>6]=p;
    __syncthreads();
    double nrm=red[0]+red[1]+red[2]+red[3];
    vj=vj/sqrt(fmax(nrm,1e-300));
    if(tid<n) V[(size_t)tid*keep+j]=vj;
    __syncthreads();
  }
}

// ---------------------------------------------------------------------------
// direct path (ru<=64), 256 threads
__global__ __launch_bounds__(256)
void k_eig_direct(double* ws, int Soff, int MPoff, int l, int ru, int keep,
                  int newoff, int Coff){
  int tid=threadIdx.x;
  double* base=ws+(size_t)blockIdx.z*SAMP_J;
  const double* S=base+Soff;
  const double* MP=base+MPoff;
  double* C=base+Coff;
  double* NM=base+newoff;
  double* V=base+O_V;
  __shared__ double K[64*LDK];
  __shared__ float W[64*LDK];
  __shared__ double evals[64]; __shared__ int idxs[64];
  __shared__ double red[4];
  int q=ru;
  for(int e=tid;e<q*q;e+=256){
    int a=e/q,b=e%q;
    K[a*LDK+b]=0.5*(S[(size_t)a*q+b]+S[(size_t)b*q+a]);
    W[a*LDK+b]=(a==b)?1.f:0.f;
  }
  __syncthreads();
  dev_jacobi(K,W,q,tid,8);
  dev_select(K,q,keep,tid,evals,idxs);
  for(int e=tid;e<ru*keep;e+=256){
    int col=e/keep, j=e%keep;
    V[e]=(double)W[col*LDK+idxs[j]];
  }
  __syncthreads();
  dev_orthV(V,ru,keep,red);
  for(int e=tid;e<keep*ru;e+=256){
    int j=e/ru, col=e%ru;
    NM[e]=V[(size_t)col*keep+j];
  }
  for(int e=tid;e<l*keep;e+=256){
    int i=e/keep, j=e%keep;
    const double* Mi=MP+(size_t)i*ru;
    double acc=0.0;
    for(int c=0;c<ru;c++) acc+=Mi[c]*V[(size_t)c*keep+j];
    C[e]=acc;
  }
}

// ---------------------------------------------------------------------------
// Yout = A * Yin  (A 256x256 f64 global; Y 256x64 f64 global), 512 threads.
__device__ void dev_smul(const double* A, const double* Yin, double* Yout,
                         double* Yt, int tid){
  double acc[32];
  int i=tid&255, j0=(tid>>8)*32;
  #pragma unroll
  for(int j=0;j<32;j++) acc[j]=0.0;
  for(int cb=0;cb<4;cb++){
    __syncthreads();
    for(int e=tid;e<4096;e+=512) Yt[e]=Yin[cb*4096+e];
    __syncthreads();
    const double* Arow=A+(size_t)i*256+cb*64;
    for(int c=0;c<64;c++){
      double sv=Arow[c];
      const double* Yr=Yt+c*64+j0;
      #pragma unroll
      for(int j=0;j<32;j++) acc[j]+=sv*Yr[j];
    }
  }
  #pragma unroll
  for(int j=0;j<32;j++) Yout[(size_t)i*64+j0+j]=acc[j];
  __syncthreads();
}

// ---------------------------------------------------------------------------
// SHIFTED CholeskyQR on Yg (256 x ncols, f64 global), 512 threads.
__device__ void dev_cholqr(double* Yg, int ncols, double* Kd, double* Yt,
                           double* Ri, int tid){
  int rowsb=4096/ncols; if(rowsb>256) rowsb=256;   // 64 (nc=64) | 128 (nc=32)
  int nblk=256/rowsb;                               // 4 | 2
  int n2=ncols*ncols;
  for(int e=tid;e<n2;e+=512) Kd[(e/ncols)*LDK+(e%ncols)]=0.0;
  for(int b=0;b<nblk;b++){
    __syncthreads();
    for(int e=tid;e<rowsb*ncols;e+=512) Yt[e]=Yg[(size_t)b*rowsb*ncols+e];
    __syncthreads();
    for(int e=tid;e<n2;e+=512){
      int a=e/ncols, cc=e%ncols;
      if(cc>=a){
        double acc=0.0;
        for(int r=0;r<rowsb;r++) acc+=Yt[r*ncols+a]*Yt[r*ncols+cc];
        Kd[a*LDK+cc]+=acc;
      }
    }
  }
  __syncthreads();
  // ---- single-wave region: lane k owns column k. ----
  if(tid<64){
    int k=tid;
    double dv=(k<ncols)? Kd[k*LDK+k] : 0.0;
    double tr=dv;
    for(int off=1;off<64;off<<=1) tr+=__shfl_xor(tr,off);
    double lam=(tr/ncols)*1e-14+1e-290;
    if(k<ncols){
      Kd[k*LDK+k]=dv+lam;
      WMEMF();
      for(int j=0;j<ncols;j++){
        double d=Kd[j*LDK+j];
        if(!(d>lam*0.25)) d=lam*0.25;
        if(k==j) Kd[j*LDK+j]=d;
        if(k>j){
          double invd=1.0/d;
          double kjk=Kd[j*LDK+k];
          for(int i=j+1;i<=k;i++)
            Kd[i*LDK+k]-=Kd[j*LDK+i]*kjk*invd;
        }
        WMEMF();
      }
      double dk=Kd[k*LDK+k];
      Yt[k]=1.0/sqrt(dk);
      WMEMF();
      for(int i=0;i<k;i++) Kd[i*LDK+k]*=Yt[i];
      Kd[k*LDK+k]=dk*Yt[k];
      WMEMF();
      Ri[k*66+k]=1.0/Kd[k*LDK+k];
      for(int i=k-1;i>=0;i--){
        double s=0.0;
        for(int kk=i+1;kk<=k;kk++) s+=Kd[i*LDK+kk]*Ri[kk*66+k];
        Ri[i*66+k]=-s/Kd[i*LDK+i];
      }
    }
  }
  __syncthreads();
  // ---- X = Y * Ri, staged. rpt == 8 at both call sites. ----
  {
    int j=tid%ncols, rg=tid/ncols;
    for(int b=0;b<nblk;b++){
      for(int e=tid;e<rowsb*ncols;e+=512) Yt[e]=Yg[(size_t)b*rowsb*ncols+e];
      __syncthreads();
      double xr[8];
      #pragma unroll
      for(int r4=0;r4<8;r4++){
        int r=rg*8+r4;
        double acc=0.0;
        for(int kk=0;kk<=j;kk++) acc+=Yt[r*ncols+kk]*Ri[kk*66+j];
        xr[r4]=acc;
      }
      __syncthreads();
      #pragma unroll
      for(int r4=0;r4<8;r4++){
        int r=rg*8+r4;
        Yg[(size_t)b*rowsb*ncols + r*ncols + j]=xr[r4];
      }
    }
  }
  __syncthreads();
}

// subspace path (ru==256): S4 precomputed by batched GEMM. Schedule:
// Ya=S4*Omega, QR2, 4x{Ya=S4*Ya; QR1}, QR, Ritz with S*Ya (S^20 filter).
__global__ __launch_bounds__(512,1)
void k_eig_sub(double* ws, int Soff, int S4off, int MPoff, int l, int keep,
               int newoff, int Coff){
  const int RU=256;
  int tid=threadIdx.x;
  double* base=ws+(size_t)blockIdx.z*SAMP_J;
  const double* S =base+Soff;
  const double* S4=base+S4off;
  const double* MP=base+MPoff;
  double* Ya=base+O_Y;
  double* Yb=base+O_Y2;
  double* V =base+O_V;
  double* C =base+Coff;
  double* NM=base+newoff;
  __shared__ double Kd[64*LDK];
  __shared__ double Ri[64*66];
  __shared__ float  Wf[64*LDK];
  __shared__ double Yt[4096];
  __shared__ unsigned long long om[256];
  __shared__ double evals[64]; __shared__ int idxs[64];

  for(int c2=tid;c2<256;c2+=512){
    unsigned long long mask=0ull;
    for(int j=0;j<64;j++){
      unsigned h=(unsigned)(c2*1103515245u)^(unsigned)((j+1)*2654435761u);
      h^=h>>13; h*=0x9E3779B1u;
      mask |= ((unsigned long long)((h>>16)&1u))<<j;
    }
    om[c2]=mask;
  }
  __syncthreads();

  for(int e=tid;e<RU*64;e+=512){
    int i=e>>6, j=e&63;
    const double* Si=S4+(size_t)i*RU;
    double acc=0.0;
    for(int c2=0;c2<RU;c2++)
      acc += ((om[c2]>>j)&1ull)? Si[c2] : -Si[c2];
    Ya[e]=acc;
  }
  __syncthreads();
  dev_cholqr(Ya,64,Kd,Yt,Ri,tid);
  dev_cholqr(Ya,64,Kd,Yt,Ri,tid);
  for(int it=0;it<4;it++){
    dev_smul(S4,Ya,Yb,Yt,tid);
    double* t=Ya; Ya=Yb; Yb=t;
    dev_cholqr(Ya,64,Kd,Yt,Ri,tid);
  }
  dev_cholqr(Ya,64,Kd,Yt,Ri,tid);
  dev_smul(S,Ya,Yb,Yt,tid);

  for(int e=tid;e<4096;e+=512){ int a=e>>6,c=e&63; Kd[a*LDK+c]=0.0; }
  for(int b=0;b<8;b++){
    __syncthreads();
    for(int e=tid;e<2048;e+=512){ Yt[e]=Ya[b*2048+e]; Yt[2048+e]=Yb[b*2048+e]; }
    __syncthreads();
    for(int e=tid;e<4096;e+=512){
      int a=e>>6, c=e&63;
      double acc=Kd[a*LDK+c];
      for(int r=0;r<32;r++) acc+=Yt[r*64+a]*Yt[2048+r*64+c];
      Kd[a*LDK+c]=acc;
    }
  }
  __syncthreads();
  for(int e=tid;e<4096;e+=512){
    int a=e>>6,c=e&63;
    if(a<c){ double m=0.5*(Kd[a*LDK+c]+Kd[c*LDK+a]); Kd[a*LDK+c]=m; Kd[c*LDK+a]=m; }
  }
  __syncthreads();
  for(int e=tid;e<4096;e+=512){ int a=e>>6,c=e&63; Wf[a*LDK+c]=(a==c)?1.f:0.f; }
  __syncthreads();
  dev_jacobi(Kd,Wf,64,tid,6);
  dev_select(Kd,64,keep,tid,evals,idxs);
  for(int e=tid;e<RU*keep;e+=512){
    int i=e/keep, j=e%keep; int vj=idxs[j];
    const double* Yr=Ya+(size_t)i*64;
    double acc=0.0;
    for(int t=0;t<64;t++) acc+=Yr[t]*(double)Wf[t*LDK+vj];
    V[e]=acc;
  }
  __syncthreads();
  dev_cholqr(V,keep,Kd,Yt,Ri,tid);
  for(int e=tid;e<keep*RU;e+=512){
    int j=e/RU, col=e%RU;
    NM[e]=V[(size_t)col*keep+j];
  }
  for(int e=tid;e<l*keep;e+=512){
    int i=e/keep, j=e%keep;
    const double* Mi=MP+(size_t)i*RU;
    double acc=0.0;
    for(int col=0;col<RU;col++) acc+=Mi[col]*V[(size_t)col*keep+j];
    C[e]=acc;
  }
}

// ---------------------------------------------------------------------------
__global__ void k_copy(double* ws){
  double* base=ws+(size_t)blockIdx.z*SAMP_J;
  for(int e=blockIdx.x*blockDim.x+threadIdx.x;e<65536;e+=gridDim.x*blockDim.x)
    base[O_CUR+e]=base[O_NEW+e];
}

__global__ __launch_bounds__(256)
void k_final(double* ws, float* out, int s0){
  int z=blockIdx.z, tid=threadIdx.x;
  const double* bot=ws+(size_t)(2*z)*SAMP_J+O_CUR;
  const double* top=ws+(size_t)(2*z+1)*SAMP_J+O_CUR;
  __shared__ double v[1024], v2[1024];
  __shared__ float w[8192];
  const int Bf[9]={1,8,32,32,32,32,32,8,1};
  if(tid==0) v[0]=1.0;
  __syncthreads();
  for(int y=0;y<8;y++){
    int a=Bf[y], b=Bf[y+1];
    const double* By=bot+y*8192;
    const double* Ty=top+y*8192;
    for(int e=tid;e<a*b*8;e+=256){
      int k2=e&7; int bb=(e>>3)%b; int cc=e/(8*b);
      double acc=0.0;
      for(int aa=0;aa<a;aa++) acc+=v[aa*a+cc]*By[(aa*b+bb)*8+k2];
      w[(cc*b+bb)*8+k2]=(float)acc;
    }
    __syncthreads();
    for(int e=tid;e<b*b;e+=256){
      int dd=e%b; int bb=e/b;
      double acc=0.0;
      for(int cc=0;cc<a;cc++)
        for(int k2=0;k2<8;k2++)
          acc+=(double)w[(cc*b+bb)*8+k2]*Ty[(cc*b+dd)*8+k2];
      v2[bb*b+dd]=acc;
    }
    __syncthreads();
    for(int e=tid;e<b*b;e+=256) v[e]=v2[e];
    __syncthreads();
  }
  if(tid==0) out[s0+z]=(float)v[0];
}

// ---------------------------------------------------------------------------
static void run_compress_dual(double* ws, const float* peps, const int* x,
                              int s0, int ns, int xib, int xit, bool first,
                              hipStream_t stream){
  int njobs=2*ns;
  int Bin[9]; Bin[0]=1; Bin[8]=1;
  for(int i=1;i<8;i++) Bin[i]= first?8:((i==1||i==7)?8:32);
  int lraw[8], rraw[8];
  for(int y=0;y<8;y++){ lraw[y]=Bin[y]*((y>0)?8:1); rraw[y]=Bin[y+1]*((y<7)?8:1); }
  int kch[8];
  { int kp=1;
    for(int y=0;y<8;y++){ int n=(y<7)?Bin[y+1]*8:1; kch[y]=imin_(kp*8,n); kp=kch[y]; } }
  int keep[8];
  keep[7]=imin_(32, imin_(kch[6], 8));
  for(int y=6;y>=1;y--) keep[y]=imin_(32, imin_(kch[y-1], keep[y+1]*8));

  // forward: G^(1..7)
  for(int y=0;y<7;y++){
    k_absorb<<<dim3(Bin[y+1],1,njobs),256,0,stream>>>(ws,peps,x,s0,xib,xit,y,Bin[y],Bin[y+1]);
    int l=lraw[y], r8=rraw[y]*8;
    k_mmGT<<<dim3((l+31)/32,(r8+31)/32,njobs),dim3(16,16),0,stream>>>(
        ws,O_GSB+goff[y],O_TF,O_H2F,l,l,r8);
    k_gacc2<<<dim3((rraw[y]+31)/32,(rraw[y]+31)/32,njobs),dim3(16,16),0,stream>>>(
        ws,O_H2F,O_TF,O_GSB+goff[y+1],l,rraw[y]);
    k_gscale<<<dim3(1,1,njobs),256,0,stream>>>(ws,O_GSB+goff[y+1],rraw[y]);
  }
  // backward
  for(int y=7;y>=1;y--){
    k_absorb<<<dim3(Bin[y+1],1,njobs),256,0,stream>>>(ws,peps,x,s0,xib,xit,y,Bin[y],Bin[y+1]);
    int ru=(y==7)?8:keep[y+1]*8;
    if(y==7) k_t2mp<<<dim3(2,1,njobs),256,0,stream>>>(ws,lraw[7]*8);
    else     k_mp<<<dim3(lraw[y],1,njobs),256,0,stream>>>(ws,O_TF,O_C,O_MP,rraw[y],keep[y+1]);
    int l=lraw[y];
    k_mm<<<dim3((l+31)/32,(ru+31)/32,njobs),dim3(16,16),0,stream>>>(
        ws,O_GSB+goff[y],O_MP,O_H,l,l,ru);
    k_mm_tn<<<dim3((ru+31)/32,(ru+31)/32,njobs),dim3(16,16),0,stream>>>(
        ws,O_MP,O_H,O_S,ru,l,ru);
    if(ru<=64){
      k_eig_direct<<<dim3(1,1,njobs),256,0,stream>>>(ws,O_S,O_MP,l,ru,keep[y],
                    O_NEW+y*8192,O_C);
    } else {
      // S2 = S*S into O_H (dead), S4 = S2*S2 into O_S4 (dead G^(6) slot)
      k_mm<<<dim3(8,8,njobs),dim3(16,16),0,stream>>>(ws,O_S,O_S,O_H,256,256,256);
      k_mm<<<dim3(8,8,njobs),dim3(16,16),0,stream>>>(ws,O_H,O_H,O_S4,256,256,256);
      k_eig_sub<<<dim3(1,1,njobs),512,0,stream>>>(ws,O_S,O_S4,O_MP,l,keep[y],
                    O_NEW+y*8192,O_C);
    }
  }
  // site 0
  k_absorb<<<dim3(Bin[1],1,njobs),256,0,stream>>>(ws,peps,x,s0,xib,xit,0,1,Bin[1]);
  k_mp<<<dim3(1,1,njobs),256,0,stream>>>(ws,O_TF,O_C,O_NEW+0,rraw[0],keep[1]);
  k_copy<<<dim3(32,1,njobs),256,0,stream>>>(ws);
}

extern "C" void kernel_launch(void* const* d_in, const int* in_sizes, int n_in,
                              void* d_out, int out_size, void* d_ws, size_t ws_size,
                              hipStream_t stream){
  const int*   x    = (const int*)d_in[0];     // (16,64) int32
  const float* peps = (const float*)d_in[1];   // (8,8,8,8,8,8,2) f32
  float* out = (float*)d_out;                  // 16 f32
  double* ws = (double*)d_ws;
  size_t samp_bytes = (size_t)2*SAMP_J*sizeof(double);
  int max_chunk=(int)(ws_size/samp_bytes);
  if(max_chunk<1) max_chunk=1;
  if(max_chunk>16) max_chunk=16;
  for(int s0=0;s0<16;s0+=max_chunk){
    int ns=imin_(max_chunk,16-s0);
    int njobs=2*ns;
    k_init_row<<<dim3(8,1,njobs),64,0,stream>>>(ws,peps,x,s0);
    run_compress_dual(ws,peps,x,s0,ns,1,6,true ,stream);
    run_compress_dual(ws,peps,x,s0,ns,2,5,false,stream);
    run_compress_dual(ws,peps,x,s0,ns,3,4,false,stream);
    k_final<<<dim3(1,1,ns),256,0,stream>>>(ws,out,s0);
  }
}

// Round 18
// 84526.929 us; speedup vs baseline: 1.1156x; 1.0183x over previous
//
#include <hip/hip_runtime.h>

// ---------------------------------------------------------------------------
// fPEPS amplitude via boundary-MPS, chi=32. Metric ("left-Gram") formulation,
// f64 core with f32 bulk-tensor storage. Truncation = top eigvecs of M'^T G M'
// via in-LDS SHIFTED CholeskyQR subspace iteration (overflow-free, f64).
// Bottom & top chains fused per launch (blockIdx.z = sample*2+side).
// Lx=Ly=8, D=8, P=2, CHI=32.
//
// R1: cholqr Rinv+staged GEMM. R2: workspace slim (single chunk).
// R4: 512-thread eig_sub, LDK=65, degree-2 schedule (->154.5k).
// R7: S2/S4 precomputed by batched k_mm (->91k). R8: barrier diet (NULL).
// R10: register-tiled batch GEMMs (->86.1k; k_mp emerged at 29ms profiled).
// R15: kill strided-global dot chains — k_mp stages C in 64-row LDS chunks;
// eig_sub epilogue C=MP*V stages V through Yt (order-preserving); cholqr
// X-phase row count fixed at ncols=8.
// R16/R17: identical resubmits (bench infra-failed; measurement pending).
// ---------------------------------------------------------------------------

__host__ __device__ static inline int imin_(int a,int b){return a<b?a:b;}

static constexpr int SAMP_J = 991296;    // 7.93 MB/job
static constexpr int O_CUR = 0;
static constexpr int O_NEW = 65536;
static constexpr int O_TF  = 131072;
static constexpr int O_H2F = 393216;
static constexpr int O_MP  = 393216;
static constexpr int O_H   = 458752;     // H = G*M'; dead after k_mm_tn -> S2 temp
static constexpr int O_S   = 524288;
static constexpr int O_Y   = 589824;
static constexpr int O_Y2  = 606208;
static constexpr int O_C   = 622592;
static constexpr int O_V   = 630784;
static constexpr int O_GSB = 655360;
static constexpr int O_S4  = O_GSB + 266241;  // dead G^(6) slot

static const int goff[8] = {0,1,4097,69633,135169,200705,266241,331777};

#define LDK 65
#define WMEMF() __asm__ volatile("" ::: "memory")

// ---------------------------------------------------------------------------
__global__ void k_init_row(double* ws, const float* peps, const int* x, int s0){
  int z=blockIdx.z, y=blockIdx.x;
  int side=z&1, samp=z>>1;
  int xi = side?7:0;
  double* base = ws + (size_t)z*SAMP_J;
  double* cur = base + O_CUR + y*8192;
  int spin = x[(s0+samp)*64 + xi*8 + y];
  const float* pb = peps + (size_t)xi*65536 + (size_t)y*8192 + spin;
  int rd=(y<7)?8:1, ld=(y>0)?8:1;
  int ntot = ld*rd*8;
  for(int e=threadIdx.x; e<ntot; e+=blockDim.x){
    int u=e&7; int r=(e>>3)%rd; int l=e/(8*rd);
    float v = side ? pb[u*128 + l*16 + r*2] : pb[u*1024 + l*16 + r*2];
    cur[e]=(double)v;
  }
  if(y==0 && threadIdx.x==0) base[O_GSB]=1.0;
}

// ---------------------------------------------------------------------------
__global__ __launch_bounds__(256)
void k_absorb(double* ws, const float* peps, const int* x, int s0,
              int xi_b, int xi_t, int y, int bl, int brdim){
  int z=blockIdx.z, yb=blockIdx.x;
  int side=z&1, samp=z>>1;
  int xi = side? xi_t : xi_b;
  int so = side? 128:1024, sc = side? 1024:128;
  double* base=ws+(size_t)z*SAMP_J;
  const double* B=base+O_CUR+y*8192;
  float* T=(float*)(base+O_TF);
  int spin=x[(s0+samp)*64+xi*8+y];
  const float* A=peps+(size_t)xi*65536+(size_t)y*8192+spin;
  int Lp=(y>0)?8:1, Rp=(y<7)?8:1;
  int rraw=brdim*Rp;
  __shared__ float As[4096];
  __shared__ double Bs[256];
  int nA=64*Lp*Rp;
  for(int e=threadIdx.x;e<nA;e+=256){
    int rp=e%Rp; int t=e/Rp; int lp=t%Lp; t/=Lp; int p=t&7; int u=t>>3;
    As[e]=A[u*so+p*sc+lp*16+rp*2];
  }
  for(int e=threadIdx.x;e<bl*8;e+=256)
    Bs[e]=B[((e>>3)*brdim+yb)*8+(e&7)];
  __syncthreads();
  int ntot=bl*Lp*Rp*8;
  for(int e=threadIdx.x;e<ntot;e+=256){
    int u=e&7; int t=e>>3; int rp=t%Rp; t/=Rp; int lp=t%Lp; int xx=t/Lp;
    double acc=0.0;
    #pragma unroll
    for(int p=0;p<8;p++) acc+=Bs[xx*8+p]*(double)As[((u*8+p)*Lp+lp)*Rp+rp];
    T[(size_t)((xx*Lp+lp)*rraw + yb*Rp+rp)*8 + u]=(float)acc;
  }
}

// ---------------------------------------------------------------------------
// H2(f32) = G(f64) * T(f32): (ni x nk)(nk x nj). 32x32 tile, 2x2 micro.
__global__ __launch_bounds__(256)
void k_mmGT(double* ws, int Aoff, int Boff, int Coff, int ni, int nk, int nj){
  double* base=ws+(size_t)blockIdx.z*SAMP_J;
  const double* A=base+Aoff;
  const float* B=(const float*)(base+Boff);
  float* C=(float*)(base+Coff);
  __shared__ double As[32][34];   // [k][i]
  __shared__ float  Bs[32][34];   // [k][j]
  int tx=threadIdx.x, ty=threadIdx.y;
  int i0=blockIdx.x*32, j0=blockIdx.y*32;
  double a00=0,a01=0,a10=0,a11=0;
  for(int k0=0;k0<nk;k0+=32){
    #pragma unroll
    for(int q=0;q<2;q++){
      int ii=ty+q*16;
      #pragma unroll
      for(int p=0;p<2;p++){
        int t=tx+p*16; int kk=k0+t;
        As[t][ii]=(i0+ii<ni && kk<nk)? A[(size_t)(i0+ii)*nk + kk] : 0.0;
      }
    }
    #pragma unroll
    for(int q=0;q<2;q++){
      int t=ty+q*16; int kk=k0+t;
      #pragma unroll
      for(int p=0;p<2;p++){
        int jj=tx+p*16;
        Bs[t][jj]=(kk<nk && j0+jj<nj)? B[(size_t)kk*nj + j0+jj] : 0.f;
      }
    }
    __syncthreads();
    #pragma unroll
    for(int t=0;t<32;t++){
      double av0=As[t][ty], av1=As[t][ty+16];
      double bv0=(double)Bs[t][tx], bv1=(double)Bs[t][tx+16];
      a00+=av0*bv0; a01+=av0*bv1; a10+=av1*bv0; a11+=av1*bv1;
    }
    __syncthreads();
  }
  if(i0+ty<ni    && j0+tx<nj)    C[(size_t)(i0+ty)*nj + j0+tx]=(float)a00;
  if(i0+ty<ni    && j0+tx+16<nj) C[(size_t)(i0+ty)*nj + j0+tx+16]=(float)a01;
  if(i0+ty+16<ni && j0+tx<nj)    C[(size_t)(i0+ty+16)*nj + j0+tx]=(float)a10;
  if(i0+ty+16<ni && j0+tx+16<nj) C[(size_t)(i0+ty+16)*nj + j0+tx+16]=(float)a11;
}

// f64 C = A*B. 32x32 tile, 2x2 micro.
__global__ __launch_bounds__(256)
void k_mm(double* ws, int Aoff, int Boff, int Coff, int ni, int nk, int nj){
  double* base=ws+(size_t)blockIdx.z*SAMP_J;
  const double* A=base+Aoff; const double* B=base+Boff; double* C=base+Coff;
  __shared__ double As[32][34];   // [k][i]
  __shared__ double Bs[32][34];   // [k][j]
  int tx=threadIdx.x, ty=threadIdx.y;
  int i0=blockIdx.x*32, j0=blockIdx.y*32;
  double a00=0,a01=0,a10=0,a11=0;
  for(int k0=0;k0<nk;k0+=32){
    #pragma unroll
    for(int q=0;q<2;q++){
      int ii=ty+q*16;
      #pragma unroll
      for(int p=0;p<2;p++){
        int t=tx+p*16; int kk=k0+t;
        As[t][ii]=(i0+ii<ni && kk<nk)? A[(size_t)(i0+ii)*nk + kk] : 0.0;
      }
    }
    #pragma unroll
    for(int q=0;q<2;q++){
      int t=ty+q*16; int kk=k0+t;
      #pragma unroll
      for(int p=0;p<2;p++){
        int jj=tx+p*16;
        Bs[t][jj]=(kk<nk && j0+jj<nj)? B[(size_t)kk*nj + j0+jj] : 0.0;
      }
    }
    __syncthreads();
    #pragma unroll
    for(int t=0;t<32;t++){
      double av0=As[t][ty], av1=As[t][ty+16];
      double bv0=Bs[t][tx], bv1=Bs[t][tx+16];
      a00+=av0*bv0; a01+=av0*bv1; a10+=av1*bv0; a11+=av1*bv1;
    }
    __syncthreads();
  }
  if(i0+ty<ni    && j0+tx<nj)    C[(size_t)(i0+ty)*nj + j0+tx]=a00;
  if(i0+ty<ni    && j0+tx+16<nj) C[(size_t)(i0+ty)*nj + j0+tx+16]=a01;
  if(i0+ty+16<ni && j0+tx<nj)    C[(size_t)(i0+ty+16)*nj + j0+tx]=a10;
  if(i0+ty+16<ni && j0+tx+16<nj) C[(size_t)(i0+ty+16)*nj + j0+tx+16]=a11;
}

// f64 C = A^T*B (A is nk x ni). 32x32 tile, 2x2 micro.
__global__ __launch_bounds__(256)
void k_mm_tn(double* ws, int Aoff, int Boff, int Coff, int ni, int nk, int nj){
  double* base=ws+(size_t)blockIdx.z*SAMP_J;
  const double* A=base+Aoff; const double* B=base+Boff; double* C=base+Coff;
  __shared__ double As[32][34];   // [k][i]
  __shared__ double Bs[32][34];   // [k][j]
  int tx=threadIdx.x, ty=threadIdx.y;
  int i0=blockIdx.x*32, j0=blockIdx.y*32;
  double a00=0,a01=0,a10=0,a11=0;
  for(int k0=0;k0<nk;k0+=32){
    #pragma unroll
    for(int q=0;q<2;q++){
      int t=ty+q*16; int kk=k0+t;
      #pragma unroll
      for(int p=0;p<2;p++){
        int ii=tx+p*16;
        As[t][ii]=(kk<nk && i0+ii<ni)? A[(size_t)kk*ni + i0+ii] : 0.0;
        Bs[t][ii]=(kk<nk && j0+ii<nj)? B[(size_t)kk*nj + j0+ii] : 0.0;
      }
    }
    __syncthreads();
    #pragma unroll
    for(int t=0;t<32;t++){
      double av0=As[t][ty], av1=As[t][ty+16];
      double bv0=Bs[t][tx], bv1=Bs[t][tx+16];
      a00+=av0*bv0; a01+=av0*bv1; a10+=av1*bv0; a11+=av1*bv1;
    }
    __syncthreads();
  }
  if(i0+ty<ni    && j0+tx<nj)    C[(size_t)(i0+ty)*nj + j0+tx]=a00;
  if(i0+ty<ni    && j0+tx+16<nj) C[(size_t)(i0+ty)*nj + j0+tx+16]=a01;
  if(i0+ty+16<ni && j0+tx<nj)    C[(size_t)(i0+ty+16)*nj + j0+tx]=a10;
  if(i0+ty+16<ni && j0+tx+16<nj) C[(size_t)(i0+ty+16)*nj + j0+tx+16]=a11;
}

// ---------------------------------------------------------------------------
// G'(f64)[r][r'] = sum_{l,u} H2f[(l r u)] * Tf[(l r' u)]; 32x32 tile, 2x2
// micro; upper blocks + mirror. rdim always multiple of 32 here.
__global__ __launch_bounds__(256)
void k_gacc2(double* ws, int H2off, int Toff, int Goff, int ldim, int rdim){
  int bx=blockIdx.x, by=blockIdx.y;
  if(by<bx) return;
  double* base=ws+(size_t)blockIdx.z*SAMP_J;
  const float* H2=(const float*)(base+H2off);
  const float* T=(const float*)(base+Toff);
  double* G=base+Goff;
  __shared__ float As[32][34], Bs[32][34];   // [k][r]
  int tx=threadIdx.x, ty=threadIdx.y;
  int r0=bx*32, r1=by*32;
  double a00=0,a01=0,a10=0,a11=0;
  int ktot=ldim*8;
  for(int k0=0;k0<ktot;k0+=32){
    #pragma unroll
    for(int q=0;q<2;q++){
      int t=ty+q*16; int kk=k0+t;
      int l2=kk>>3, u=kk&7;
      bool ok=kk<ktot;
      #pragma unroll
      for(int p=0;p<2;p++){
        int rr=tx+p*16;
        As[t][rr]= ok? H2[((size_t)l2*rdim + r0+rr)*8 + u] : 0.f;
        Bs[t][rr]= ok? T [((size_t)l2*rdim + r1+rr)*8 + u] : 0.f;
      }
    }
    __syncthreads();
    #pragma unroll
    for(int t=0;t<32;t++){
      double av0=(double)As[t][ty], av1=(double)As[t][ty+16];
      double bv0=(double)Bs[t][tx], bv1=(double)Bs[t][tx+16];
      a00+=av0*bv0; a01+=av0*bv1; a10+=av1*bv0; a11+=av1*bv1;
    }
    __syncthreads();
  }
  G[(size_t)(r0+ty)*rdim + r1+tx]=a00;
  G[(size_t)(r0+ty)*rdim + r1+tx+16]=a01;
  G[(size_t)(r0+ty+16)*rdim + r1+tx]=a10;
  G[(size_t)(r0+ty+16)*rdim + r1+tx+16]=a11;
  if(by>bx){
    G[(size_t)(r1+tx)*rdim + r0+ty]=a00;
    G[(size_t)(r1+tx+16)*rdim + r0+ty]=a01;
    G[(size_t)(r1+tx)*rdim + r0+ty+16]=a10;
    G[(size_t)(r1+tx+16)*rdim + r0+ty+16]=a11;
  }
}

__global__ void k_gscale(double* ws, int Goff, int n){
  int tid=threadIdx.x;
  double* base=ws+(size_t)blockIdx.z*SAMP_J;
  double* G=base+Goff;
  __shared__ double red[256]; __shared__ double s_sc;
  double mx=0.0;
  for(int i=tid;i<n;i+=256) mx=fmax(mx,fabs(G[(size_t)i*n+i]));
  red[tid]=mx; __syncthreads();
  for(int w=128;w>0;w>>=1){ if(tid<w) red[tid]=fmax(red[tid],red[tid+w]); __syncthreads(); }
  if(tid==0) s_sc=(red[0]>0.0)?1.0/red[0]:1.0;
  __syncthreads();
  double sc=s_sc;
  for(int e=tid;e<n*n;e+=256) G[e]*=sc;
}

// ---------------------------------------------------------------------------
// M(f64)[li][(k*8+u)] = sum_r Tf[(li*rraw+r)*8+u] * C[r*keep+k]
// R15: C staged through LDS in 64-row chunks (was 256B-stride global reads).
__global__ __launch_bounds__(256)
void k_mp(double* ws, int Toff, int Coff, int Moff, int rraw, int keep){
  int li=blockIdx.x, tid=threadIdx.x;
  double* base=ws+(size_t)blockIdx.z*SAMP_J;
  const float* T=(const float*)(base+Toff) + (size_t)li*rraw*8;
  const double* Cc=base+Coff;
  double* M=base+Moff+(size_t)li*keep*8;
  __shared__ float Ts[2048];
  __shared__ double Cs[64*32];       // 16 KB: 64-row chunk of C
  for(int e=tid;e<rraw*8;e+=256) Ts[e]=T[e];
  int u=tid&7, k=tid>>3;
  double acc=0.0;
  for(int r0=0;r0<rraw;r0+=64){
    int rows=imin_(64,rraw-r0);
    __syncthreads();
    for(int e=tid;e<rows*keep;e+=256)
      Cs[e]=Cc[(size_t)(r0+e/keep)*keep+(e%keep)];
    __syncthreads();
    if(tid<keep*8){
      for(int r=0;r<rows;r++)
        acc+=(double)Ts[(r0+r)*8+u]*Cs[r*keep+k];
    }
  }
  if(tid<keep*8) M[(size_t)k*8+u]=acc;
}

__global__ void k_t2mp(double* ws, int n){
  double* base=ws+(size_t)blockIdx.z*SAMP_J;
  const float* T=(const float*)(base+O_TF);
  for(int e=blockIdx.x*blockDim.x+threadIdx.x;e<n;e+=gridDim.x*blockDim.x)
    base[O_MP+e]=(double)T[e];
}

// ---------------------------------------------------------------------------
// Cyclic Jacobi, closed-form round-robin (circle method), stride LDK.
// 2 barriers/round.
__device__ void dev_jacobi(double* K, float* W, int q, int tid, int sweeps){
  int NT=blockDim.x;
  int m=q-1, npairs=q>>1;
  int L=NT/npairs;
  int inv2=(m+1)>>1;
  int pr=tid/L, lane=tid%L;
  for(int sweep=0;sweep<sweeps;sweep++)
  for(int rnd=0;rnd<m;rnd++){
    int i0=(int)(((long long)rnd*(long long)inv2)%m);
    int p,qq;
    if(pr==0){ p=i0; qq=q-1; }
    else {
      p=i0+pr; if(p>=m) p-=m;
      qq=i0-pr; if(qq<0) qq+=m;
    }
    if(p>qq){int t=p;p=qq;qq=t;}
    double c=1.0,s2=0.0;
    double apq=K[p*LDK+qq];
    double app=K[p*LDK+p], aqq=K[qq*LDK+qq];
    if(fabs(apq) > 1e-18*(fabs(app)+fabs(aqq))+1e-300){
      double tau=(aqq-app)/(2.0*apq);
      double t=(tau>=0.0?1.0:-1.0)/(fabs(tau)+sqrt(1.0+tau*tau));
      c=1.0/sqrt(1.0+t*t); s2=t*c;
    }
    for(int j=lane;j<q;j+=L){
      double kp=K[p*LDK+j], kq=K[qq*LDK+j];
      K[p*LDK+j]=c*kp-s2*kq; K[qq*LDK+j]=s2*kp+c*kq;
    }
    __syncthreads();
    {
      float cf=(float)c, sf=(float)s2;
      for(int j=lane;j<q;j+=L){
        double kp=K[j*LDK+p], kq=K[j*LDK+qq];
        K[j*LDK+p]=c*kp-s2*kq; K[j*LDK+qq]=s2*kp+c*kq;
        float wp=W[j*LDK+p], wq=W[j*LDK+qq];
        W[j*LDK+p]=cf*wp-sf*wq; W[j*LDK+qq]=sf*wp+cf*wq;
      }
    }
    __syncthreads();
  }
}

// parallel top-keep select: wave-0 argmax per pick
__device__ void dev_select(const double* K, int q, int keep, int tid,
                           double* evals, int* idxs){
  for(int a=tid;a<q;a+=blockDim.x) evals[a]=K[a*LDK+a];
  __syncthreads();
  if(tid<64){
    int a=tid;
    double v=(a<q)? evals[a] : -1.0e300;
    for(int j=0;j<keep;j++){
      double bv=v; int bi=a;
      for(int off=1;off<64;off<<=1){
        double ov=__shfl_xor(bv,off); int oi=__shfl_xor(bi,off);
        if(ov>bv || (ov==bv && oi<bi)){ bv=ov; bi=oi; }
      }
      if(a==bi) v=-1.0e300;
      if(tid==0) idxs[j]=bi;
    }
  }
  __syncthreads();
}

// f64 CGS2 of V columns (n rows, keep cols, row-major stride keep) [256 thr]
__device__ void dev_orthV(double* V, int n, int keep, double* red){
  int tid=threadIdx.x;
  for(int j=0;j<keep;j++){
    double vj=(tid<n)? V[(size_t)tid*keep+j] : 0.0;
    for(int pass=0;pass<2;pass++){
      for(int t=0;t<j;t++){
        double vt=(tid<n)? V[(size_t)tid*keep+t] : 0.0;
        double p=vj*vt;
        for(int off=1;off<64;off<<=1) p+=__shfl_xor(p,off);
        if((tid&63)==0) red[tid>>6]=p;
        __syncthreads();
        double d=red[0]+red[1]+red[2]+red[3];
        vj-=d*vt;
        __syncthreads();
      }
    }
    double p=vj*vj;
    for(int off=1;off<64;off<<=1) p+=__shfl_xor(p,off);
    if((tid&63)==0) red[tid>>6]=p;
    __syncthreads();
    double nrm=red[0]+red[1]+red[2]+red[3];
    vj=vj/sqrt(fmax(nrm,1e-300));
    if(tid<n) V[(size_t)tid*keep+j]=vj;
    __syncthreads();
  }
}

// ---------------------------------------------------------------------------
// direct path (ru<=64), 256 threads
__global__ __launch_bounds__(256)
void k_eig_direct(double* ws, int Soff, int MPoff, int l, int ru, int keep,
                  int newoff, int Coff){
  int tid=threadIdx.x;
  double* base=ws+(size_t)blockIdx.z*SAMP_J;
  const double* S=base+Soff;
  const double* MP=base+MPoff;
  double* C=base+Coff;
  double* NM=base+newoff;
  double* V=base+O_V;
  __shared__ double K[64*LDK];
  __shared__ float W[64*LDK];
  __shared__ double evals[64]; __shared__ int idxs[64];
  __shared__ double red[4];
  int q=ru;
  for(int e=tid;e<q*q;e+=256){
    int a=e/q,b=e%q;
    K[a*LDK+b]=0.5*(S[(size_t)a*q+b]+S[(size_t)b*q+a]);
    W[a*LDK+b]=(a==b)?1.f:0.f;
  }
  __syncthreads();
  dev_jacobi(K,W,q,tid,8);
  dev_select(K,q,keep,tid,evals,idxs);
  for(int e=tid;e<ru*keep;e+=256){
    int col=e/keep, j=e%keep;
    V[e]=(double)W[col*LDK+idxs[j]];
  }
  __syncthreads();
  dev_orthV(V,ru,keep,red);
  for(int e=tid;e<keep*ru;e+=256){
    int j=e/ru, col=e%ru;
    NM[e]=V[(size_t)col*keep+j];
  }
  for(int e=tid;e<l*keep;e+=256){
    int i=e/keep, j=e%keep;
    const double* Mi=MP+(size_t)i*ru;
    double acc=0.0;
    for(int c=0;c<ru;c++) acc+=Mi[c]*V[(size_t)c*keep+j];
    C[e]=acc;
  }
}

// ---------------------------------------------------------------------------
// Yout = A * Yin  (A 256x256 f64 global; Y 256x64 f64 global), 512 threads.
__device__ void dev_smul(const double* A, const double* Yin, double* Yout,
                         double* Yt, int tid){
  double acc[32];
  int i=tid&255, j0=(tid>>8)*32;
  #pragma unroll
  for(int j=0;j<32;j++) acc[j]=0.0;
  for(int cb=0;cb<4;cb++){
    __syncthreads();
    for(int e=tid;e<4096;e+=512) Yt[e]=Yin[cb*4096+e];
    __syncthreads();
    const double* Arow=A+(size_t)i*256+cb*64;
    for(int c=0;c<64;c++){
      double sv=Arow[c];
      const double* Yr=Yt+c*64+j0;
      #pragma unroll
      for(int j=0;j<32;j++) acc[j]+=sv*Yr[j];
    }
  }
  #pragma unroll
  for(int j=0;j<32;j++) Yout[(size_t)i*64+j0+j]=acc[j];
  __syncthreads();
}

// ---------------------------------------------------------------------------
// SHIFTED CholeskyQR on Yg (256 x ncols, f64 global), 512 threads.
__device__ void dev_cholqr(double* Yg, int ncols, double* Kd, double* Yt,
                           double* Ri, int tid){
  int rowsb=4096/ncols; if(rowsb>256) rowsb=256;   // 64 (nc=64) | 256 (nc<=16..32)
  int nblk=256/rowsb;                               // 4 | 1..2
  int n2=ncols*ncols;
  for(int e=tid;e<n2;e+=512) Kd[(e/ncols)*LDK+(e%ncols)]=0.0;
  for(int b=0;b<nblk;b++){
    __syncthreads();
    for(int e=tid;e<rowsb*ncols;e+=512) Yt[e]=Yg[(size_t)b*rowsb*ncols+e];
    __syncthreads();
    for(int e=tid;e<n2;e+=512){
      int a=e/ncols, cc=e%ncols;
      if(cc>=a){
        double acc=0.0;
        for(int r=0;r<rowsb;r++) acc+=Yt[r*ncols+a]*Yt[r*ncols+cc];
        Kd[a*LDK+cc]+=acc;
      }
    }
  }
  __syncthreads();
  // ---- single-wave region: lane k owns column k. ----
  if(tid<64){
    int k=tid;
    double dv=(k<ncols)? Kd[k*LDK+k] : 0.0;
    double tr=dv;
    for(int off=1;off<64;off<<=1) tr+=__shfl_xor(tr,off);
    double lam=(tr/ncols)*1e-14+1e-290;
    if(k<ncols){
      Kd[k*LDK+k]=dv+lam;
      WMEMF();
      for(int j=0;j<ncols;j++){
        double d=Kd[j*LDK+j];
        if(!(d>lam*0.25)) d=lam*0.25;
        if(k==j) Kd[j*LDK+j]=d;
        if(k>j){
          double invd=1.0/d;
          double kjk=Kd[j*LDK+k];
          for(int i=j+1;i<=k;i++)
            Kd[i*LDK+k]-=Kd[j*LDK+i]*kjk*invd;
        }
        WMEMF();
      }
      double dk=Kd[k*LDK+k];
      Yt[k]=1.0/sqrt(dk);
      WMEMF();
      for(int i=0;i<k;i++) Kd[i*LDK+k]*=Yt[i];
      Kd[k*LDK+k]=dk*Yt[k];
      WMEMF();
      Ri[k*66+k]=1.0/Kd[k*LDK+k];
      for(int i=k-1;i>=0;i--){
        double s=0.0;
        for(int kk=i+1;kk<=k;kk++) s+=Kd[i*LDK+kk]*Ri[kk*66+k];
        Ri[i*66+k]=-s/Kd[i*LDK+i];
      }
    }
  }
  __syncthreads();
  // ---- X = Y * Ri, staged. rpt = rowsb*ncols/512 (8 at nc=64, 4 at nc=8). ----
  {
    int j=tid%ncols, rg=tid/ncols;
    int rpt=(rowsb*ncols)/512;
    for(int b=0;b<nblk;b++){
      for(int e=tid;e<rowsb*ncols;e+=512) Yt[e]=Yg[(size_t)b*rowsb*ncols+e];
      __syncthreads();
      double xr[8];
      #pragma unroll
      for(int r4=0;r4<8;r4++){
        if(r4<rpt){
          int r=rg*rpt+r4;
          double acc=0.0;
          for(int kk=0;kk<=j;kk++) acc+=Yt[r*ncols+kk]*Ri[kk*66+j];
          xr[r4]=acc;
        }
      }
      __syncthreads();
      #pragma unroll
      for(int r4=0;r4<8;r4++){
        if(r4<rpt){
          int r=rg*rpt+r4;
          Yg[(size_t)b*rowsb*ncols + r*ncols + j]=xr[r4];
        }
      }
    }
  }
  __syncthreads();
}

// subspace path (ru==256): S4 precomputed by batched GEMM. Schedule:
// Ya=S4*Omega, QR2, 4x{Ya=S4*Ya; QR1}, QR, Ritz with S*Ya (S^20 filter).
// R15: epilogue C=MP*V stages V through Yt (order-preserving).
__global__ __launch_bounds__(512,1)
void k_eig_sub(double* ws, int Soff, int S4off, int MPoff, int l, int keep,
               int newoff, int Coff){
  const int RU=256;
  int tid=threadIdx.x;
  double* base=ws+(size_t)blockIdx.z*SAMP_J;
  const double* S =base+Soff;
  const double* S4=base+S4off;
  const double* MP=base+MPoff;
  double* Ya=base+O_Y;
  double* Yb=base+O_Y2;
  double* V =base+O_V;
  double* C =base+Coff;
  double* NM=base+newoff;
  __shared__ double Kd[64*LDK];
  __shared__ double Ri[64*66];
  __shared__ float  Wf[64*LDK];
  __shared__ double Yt[4096];
  __shared__ unsigned long long om[256];
  __shared__ double evals[64]; __shared__ int idxs[64];

  for(int c2=tid;c2<256;c2+=512){
    unsigned long long mask=0ull;
    for(int j=0;j<64;j++){
      unsigned h=(unsigned)(c2*1103515245u)^(unsigned)((j+1)*2654435761u);
      h^=h>>13; h*=0x9E3779B1u;
      mask |= ((unsigned long long)((h>>16)&1u))<<j;
    }
    om[c2]=mask;
  }
  __syncthreads();

  for(int e=tid;e<RU*64;e+=512){
    int i=e>>6, j=e&63;
    const double* Si=S4+(size_t)i*RU;
    double acc=0.0;
    for(int c2=0;c2<RU;c2++)
      acc += ((om[c2]>>j)&1ull)? Si[c2] : -Si[c2];
    Ya[e]=acc;
  }
  __syncthreads();
  dev_cholqr(Ya,64,Kd,Yt,Ri,tid);
  dev_cholqr(Ya,64,Kd,Yt,Ri,tid);
  for(int it=0;it<4;it++){
    dev_smul(S4,Ya,Yb,Yt,tid);
    double* t=Ya; Ya=Yb; Yb=t;
    dev_cholqr(Ya,64,Kd,Yt,Ri,tid);
  }
  dev_cholqr(Ya,64,Kd,Yt,Ri,tid);
  dev_smul(S,Ya,Yb,Yt,tid);

  for(int e=tid;e<4096;e+=512){ int a=e>>6,c=e&63; Kd[a*LDK+c]=0.0; }
  for(int b=0;b<8;b++){
    __syncthreads();
    for(int e=tid;e<2048;e+=512){ Yt[e]=Ya[b*2048+e]; Yt[2048+e]=Yb[b*2048+e]; }
    __syncthreads();
    for(int e=tid;e<4096;e+=512){
      int a=e>>6, c=e&63;
      double acc=Kd[a*LDK+c];
      for(int r=0;r<32;r++) acc+=Yt[r*64+a]*Yt[2048+r*64+c];
      Kd[a*LDK+c]=acc;
    }
  }
  __syncthreads();
  for(int e=tid;e<4096;e+=512){
    int a=e>>6,c=e&63;
    if(a<c){ double m=0.5*(Kd[a*LDK+c]+Kd[c*LDK+a]); Kd[a*LDK+c]=m; Kd[c*LDK+a]=m; }
  }
  __syncthreads();
  for(int e=tid;e<4096;e+=512){ int a=e>>6,c=e&63; Wf[a*LDK+c]=(a==c)?1.f:0.f; }
  __syncthreads();
  dev_jacobi(Kd,Wf,64,tid,6);
  dev_select(Kd,64,keep,tid,evals,idxs);
  for(int e=tid;e<RU*keep;e+=512){
    int i=e/keep, j=e%keep; int vj=idxs[j];
    const double* Yr=Ya+(size_t)i*64;
    double acc=0.0;
    for(int t=0;t<64;t++) acc+=Yr[t]*(double)Wf[t*LDK+vj];
    V[e]=acc;
  }
  __syncthreads();
  dev_cholqr(V,keep,Kd,Yt,Ri,tid);
  for(int e=tid;e<keep*RU;e+=512){
    int j=e/RU, col=e%RU;
    NM[e]=V[(size_t)col*keep+j];
  }
  __syncthreads();
  // C = MP * V, V staged through Yt in 128-row chunks (col order preserved)
  {
    int nout=l*keep;                    // <= 8192
    double accv[16];
    #pragma unroll
    for(int q=0;q<16;q++) accv[q]=0.0;
    for(int ch=0;ch<2;ch++){
      __syncthreads();
      for(int e=tid;e<128*keep;e+=512)
        Yt[e]=V[(size_t)(ch*128+e/keep)*keep+(e%keep)];
      __syncthreads();
      #pragma unroll
      for(int q=0;q<16;q++){
        int e=tid+q*512;
        if(e<nout){
          int i=e/keep, j=e%keep;
          const double* Mi=MP+(size_t)i*RU+ch*128;
          for(int col=0;col<128;col++) accv[q]+=Mi[col]*Yt[col*keep+j];
        }
      }
    }
    #pragma unroll
    for(int q=0;q<16;q++){
      int e=tid+q*512;
      if(e<nout) C[e]=accv[q];
    }
  }
}

// ---------------------------------------------------------------------------
__global__ void k_copy(double* ws){
  double* base=ws+(size_t)blockIdx.z*SAMP_J;
  for(int e=blockIdx.x*blockDim.x+threadIdx.x;e<65536;e+=gridDim.x*blockDim.x)
    base[O_CUR+e]=base[O_NEW+e];
}

__global__ __launch_bounds__(256)
void k_final(double* ws, float* out, int s0){
  int z=blockIdx.z, tid=threadIdx.x;
  const double* bot=ws+(size_t)(2*z)*SAMP_J+O_CUR;
  const double* top=ws+(size_t)(2*z+1)*SAMP_J+O_CUR;
  __shared__ double v[1024], v2[1024];
  __shared__ float w[8192];
  const int Bf[9]={1,8,32,32,32,32,32,8,1};
  if(tid==0) v[0]=1.0;
  __syncthreads();
  for(int y=0;y<8;y++){
    int a=Bf[y], b=Bf[y+1];
    const double* By=bot+y*8192;
    const double* Ty=top+y*8192;
    for(int e=tid;e<a*b*8;e+=256){
      int k2=e&7; int bb=(e>>3)%b; int cc=e/(8*b);
      double acc=0.0;
      for(int aa=0;aa<a;aa++) acc+=v[aa*a+cc]*By[(aa*b+bb)*8+k2];
      w[(cc*b+bb)*8+k2]=(float)acc;
    }
    __syncthreads();
    for(int e=tid;e<b*b;e+=256){
      int dd=e%b; int bb=e/b;
      double acc=0.0;
      for(int cc=0;cc<a;cc++)
        for(int k2=0;k2<8;k2++)
          acc+=(double)w[(cc*b+bb)*8+k2]*Ty[(cc*b+dd)*8+k2];
      v2[bb*b+dd]=acc;
    }
    __syncthreads();
    for(int e=tid;e<b*b;e+=256) v[e]=v2[e];
    __syncthreads();
  }
  if(tid==0) out[s0+z]=(float)v[0];
}

// ---------------------------------------------------------------------------
static void run_compress_dual(double* ws, const float* peps, const int* x,
                              int s0, int ns, int xib, int xit, bool first,
                              hipStream_t stream){
  int njobs=2*ns;
  int Bin[9]; Bin[0]=1; Bin[8]=1;
  for(int i=1;i<8;i++) Bin[i]= first?8:((i==1||i==7)?8:32);
  int lraw[8], rraw[8];
  for(int y=0;y<8;y++){ lraw[y]=Bin[y]*((y>0)?8:1); rraw[y]=Bin[y+1]*((y<7)?8:1); }
  int kch[8];
  { int kp=1;
    for(int y=0;y<8;y++){ int n=(y<7)?Bin[y+1]*8:1; kch[y]=imin_(kp*8,n); kp=kch[y]; } }
  int keep[8];
  keep[7]=imin_(32, imin_(kch[6], 8));
  for(int y=6;y>=1;y--) keep[y]=imin_(32, imin_(kch[y-1], keep[y+1]*8));

  // forward: G^(1..7)
  for(int y=0;y<7;y++){
    k_absorb<<<dim3(Bin[y+1],1,njobs),256,0,stream>>>(ws,peps,x,s0,xib,xit,y,Bin[y],Bin[y+1]);
    int l=lraw[y], r8=rraw[y]*8;
    k_mmGT<<<dim3((l+31)/32,(r8+31)/32,njobs),dim3(16,16),0,stream>>>(
        ws,O_GSB+goff[y],O_TF,O_H2F,l,l,r8);
    k_gacc2<<<dim3((rraw[y]+31)/32,(rraw[y]+31)/32,njobs),dim3(16,16),0,stream>>>(
        ws,O_H2F,O_TF,O_GSB+goff[y+1],l,rraw[y]);
    k_gscale<<<dim3(1,1,njobs),256,0,stream>>>(ws,O_GSB+goff[y+1],rraw[y]);
  }
  // backward
  for(int y=7;y>=1;y--){
    k_absorb<<<dim3(Bin[y+1],1,njobs),256,0,stream>>>(ws,peps,x,s0,xib,xit,y,Bin[y],Bin[y+1]);
    int ru=(y==7)?8:keep[y+1]*8;
    if(y==7) k_t2mp<<<dim3(2,1,njobs),256,0,stream>>>(ws,lraw[7]*8);
    else     k_mp<<<dim3(lraw[y],1,njobs),256,0,stream>>>(ws,O_TF,O_C,O_MP,rraw[y],keep[y+1]);
    int l=lraw[y];
    k_mm<<<dim3((l+31)/32,(ru+31)/32,njobs),dim3(16,16),0,stream>>>(
        ws,O_GSB+goff[y],O_MP,O_H,l,l,ru);
    k_mm_tn<<<dim3((ru+31)/32,(ru+31)/32,njobs),dim3(16,16),0,stream>>>(
        ws,O_MP,O_H,O_S,ru,l,ru);
    if(ru<=64){
      k_eig_direct<<<dim3(1,1,njobs),256,0,stream>>>(ws,O_S,O_MP,l,ru,keep[y],
                    O_NEW+y*8192,O_C);
    } else {
      // S2 = S*S into O_H (dead), S4 = S2*S2 into O_S4 (dead G^(6) slot)
      k_mm<<<dim3(8,8,njobs),dim3(16,16),0,stream>>>(ws,O_S,O_S,O_H,256,256,256);
      k_mm<<<dim3(8,8,njobs),dim3(16,16),0,stream>>>(ws,O_H,O_H,O_S4,256,256,256);
      k_eig_sub<<<dim3(1,1,njobs),512,0,stream>>>(ws,O_S,O_S4,O_MP,l,keep[y],
                    O_NEW+y*8192,O_C);
    }
  }
  // site 0
  k_absorb<<<dim3(Bin[1],1,njobs),256,0,stream>>>(ws,peps,x,s0,xib,xit,0,1,Bin[1]);
  k_mp<<<dim3(1,1,njobs),256,0,stream>>>(ws,O_TF,O_C,O_NEW+0,rraw[0],keep[1]);
  k_copy<<<dim3(32,1,njobs),256,0,stream>>>(ws);
}

extern "C" void kernel_launch(void* const* d_in, const int* in_sizes, int n_in,
                              void* d_out, int out_size, void* d_ws, size_t ws_size,
                              hipStream_t stream){
  const int*   x    = (const int*)d_in[0];     // (16,64) int32
  const float* peps = (const float*)d_in[1];   // (8,8,8,8,8,8,2) f32
  float* out = (float*)d_out;                  // 16 f32
  double* ws = (double*)d_ws;
  size_t samp_bytes = (size_t)2*SAMP_J*sizeof(double);
  int max_chunk=(int)(ws_size/samp_bytes);
  if(max_chunk<1) max_chunk=1;
  if(max_chunk>16) max_chunk=16;
  for(int s0=0;s0<16;s0+=max_chunk){
    int ns=imin_(max_chunk,16-s0);
    int njobs=2*ns;
    k_init_row<<<dim3(8,1,njobs),64,0,stream>>>(ws,peps,x,s0);
    run_compress_dual(ws,peps,x,s0,ns,1,6,true ,stream);
    run_compress_dual(ws,peps,x,s0,ns,2,5,false,stream);
    run_compress_dual(ws,peps,x,s0,ns,3,4,false,stream);
    k_final<<<dim3(1,1,ns),256,0,stream>>>(ws,out,s0);
  }
}